// Round 10
// baseline (971.365 us; speedup 1.0000x reference)
//
#include <hip/hip_runtime.h>
#include <hip/hip_bf16.h>
#include <math.h>

#define DEV static __device__ __forceinline__

typedef unsigned short u16;
typedef __attribute__((ext_vector_type(8))) __bf16 bf16x8;
typedef __attribute__((ext_vector_type(8))) unsigned short u16x8;
typedef __attribute__((ext_vector_type(4))) unsigned short u16x4;
typedef __attribute__((ext_vector_type(4))) float f32x4;
typedef __attribute__((ext_vector_type(4))) int i32x4;

constexpr int SL  = 2048;   // seq len
constexpr int DM  = 768;    // d_model
constexpr int DH  = 64;     // longformer head dim
constexpr int DFF = 3072;
constexpr int DKM = 768;    // outer-MHA head dim

DEV float b2f(u16 u){ union{float f; unsigned u;} c; c.u = ((unsigned)u)<<16; return c.f; }
DEV u16 f2b(float f){ union{float f; unsigned u;} c; c.f=f; unsigned r=(c.u + 0x7fffu + ((c.u>>16)&1u))>>16; return (u16)r; }

DEV void gld16(u16* lds, const u16* g){
  __builtin_amdgcn_global_load_lds((const __attribute__((address_space(1))) void*)g,
                                   (__attribute__((address_space(3))) void*)lds, 16, 0, 0);
}

// ---------------- reductions ----------------
DEV float wred_sum(float v){
#pragma unroll
  for (int o=32;o;o>>=1) v += __shfl_xor(v,o,64);
  return v;
}
DEV float wred_max(float v){
#pragma unroll
  for (int o=32;o;o>>=1) v = fmaxf(v, __shfl_xor(v,o,64));
  return v;
}
DEV float bred_sum(float v, float* sm){
  v = wred_sum(v);
  if ((threadIdx.x & 63)==0) sm[threadIdx.x>>6] = v;
  __syncthreads();
  float r = sm[0]+sm[1]+sm[2]+sm[3];
  __syncthreads();
  return r;
}

#define PHASE_SYNC \
  __builtin_amdgcn_s_barrier(); \
  asm volatile("s_waitcnt lgkmcnt(0)" ::: "memory"); \
  __builtin_amdgcn_sched_barrier(0); \
  __builtin_amdgcn_s_setprio(1);
#define PHASE_END \
  __builtin_amdgcn_s_setprio(0); \
  __builtin_amdgcn_s_barrier();

// ================= 256x256 8-phase BK=64 MFMA GEMM =================
// MODE 0: dense.  1: MHA scores (z=(b,h)).  3: 3-way col scatter (3072 segs).
// EPI 1: bf16. 2: fast-gelu+bf16. 3: *1/sqrt(768)+bf16.  (bf16 out only)
// Epilogue: LDS-staged (two 128-row passes, chunk-XOR swizzle) -> coalesced
// u16x8 stores. K-loop ends with s_barrier and drained vmcnt -> LDS reuse safe.
#define MFMA_PH(MH, NH) \
  { _Pragma("unroll") for (int mi2=0; mi2<4; ++mi2) { \
      _Pragma("unroll") for (int ni2=0; ni2<2; ++ni2) { \
        acc[(MH)*4+mi2][(NH)*2+ni2] = __builtin_amdgcn_mfma_f32_16x16x32_bf16(Af[mi2][0], Bf[(NH)*2+ni2][0], acc[(MH)*4+mi2][(NH)*2+ni2], 0,0,0); \
        acc[(MH)*4+mi2][(NH)*2+ni2] = __builtin_amdgcn_mfma_f32_16x16x32_bf16(Af[mi2][1], Bf[(NH)*2+ni2][1], acc[(MH)*4+mi2][(NH)*2+ni2], 0,0,0); } } }

template<int MODE, int EPI>
__global__ __launch_bounds__(512,2) void gemm256_k(
    const u16* __restrict__ A, const u16* __restrict__ Bt,
    float* __restrict__ Cf, u16* __restrict__ Cb,
    u16* __restrict__ Cb2, u16* __restrict__ Cb3,
    int K, int lda, int ldb, int ldc)
{
  extern __shared__ u16 lds_dyn[];           // [2][256][64] A | [2][256][64] B
  const int tid = threadIdx.x, lane = tid & 63, wv = tid >> 6;
  const int wr = wv >> 2, wc = wv & 3;
  const int m0 = blockIdx.x * 256, n0 = blockIdx.y * 256, z = blockIdx.z;
  const int nt = K >> 6;

  long long baseA = 0, baseB = 0;
  if constexpr (MODE==1) { int bb=z>>2, hh=z&3; baseA=(long long)bb*SL*3072 + hh*DKM; baseB=baseA; }

  const int rb = (wv*64 + lane) >> 3;
  const int sg = ((lane & 7) ^ (rb & 7)) * 8;
  const int rd0 = (lane & 15)*64 + (((lane>>4) ^ (lane & 7)) * 8);
  const int rd1 = rd0 ^ 32;

  auto stageA = [&](int buf, int half, int kt) {
#pragma unroll
    for (int tt = 0; tt < 2; ++tt) {
      const int t = half + tt*2;             // INTERLEAVED halves: h0={0,2}, h1={1,3}
      gld16(lds_dyn + buf*16384 + t*4096 + wv*512,
            A + baseA + (long long)(m0 + t*64 + rb)*lda + (long long)kt*64 + sg);
    }
  };
  auto stageB = [&](int buf, int half, int kt) {
#pragma unroll
    for (int tt = 0; tt < 2; ++tt) {
      const int t = half*2 + tt;             // contiguous (all B reads finish by end of Q1)
      gld16(lds_dyn + 32768 + buf*16384 + t*4096 + wv*512,
            Bt + baseB + (long long)(n0 + t*64 + rb)*ldb + (long long)kt*64 + sg);
    }
  };

  f32x4 acc[8][4] = {};
  bf16x8 Af[4][2];
  bf16x8 Bf[4][2];

  stageA(0,0,0); stageB(0,0,0); stageB(0,1,0); stageA(0,1,0);
  stageA(1,0,1); stageB(1,0,1); stageB(1,1,1);
  asm volatile("s_waitcnt vmcnt(6)" ::: "memory");
  __builtin_amdgcn_s_barrier();

  for (int t = 0; t < nt; ++t) {
    const int d = t & 1;
    const u16* As_d = lds_dyn + d*16384;
    const u16* Bs_d = lds_dyn + 32768 + d*16384;
#pragma unroll
    for (int mi2=0; mi2<4; ++mi2) {
      const u16* p = As_d + (wr*128 + mi2*16)*64;
      Af[mi2][0] = *(const bf16x8*)(p + rd0);
      Af[mi2][1] = *(const bf16x8*)(p + rd1);
    }
#pragma unroll
    for (int ni2=0; ni2<2; ++ni2) {
      const u16* p = Bs_d + (wc*64 + ni2*16)*64;
      Bf[ni2][0] = *(const bf16x8*)(p + rd0);
      Bf[ni2][1] = *(const bf16x8*)(p + rd1);
    }
    if (t+1 < nt) stageA(d^1, 1, t+1);
    PHASE_SYNC; MFMA_PH(0,0); PHASE_END;
#pragma unroll
    for (int ni2=0; ni2<2; ++ni2) {
      const u16* p = Bs_d + (wc*64 + 32 + ni2*16)*64;
      Bf[2+ni2][0] = *(const bf16x8*)(p + rd0);
      Bf[2+ni2][1] = *(const bf16x8*)(p + rd1);
    }
    if (t+2 < nt) stageA(d, 0, t+2);
    PHASE_SYNC; MFMA_PH(0,1); PHASE_END;
#pragma unroll
    for (int mi2=0; mi2<4; ++mi2) {
      const u16* p = As_d + (wr*128 + 64 + mi2*16)*64;
      Af[mi2][0] = *(const bf16x8*)(p + rd0);
      Af[mi2][1] = *(const bf16x8*)(p + rd1);
    }
    if (t+2 < nt) stageB(d, 0, t+2);
    PHASE_SYNC; MFMA_PH(1,0); PHASE_END;
    if (t+2 < nt) stageB(d, 1, t+2);
    __builtin_amdgcn_s_barrier();
    __builtin_amdgcn_s_setprio(1);
    MFMA_PH(1,1);
    __builtin_amdgcn_s_setprio(0);
    if (t+2 < nt)      { asm volatile("s_waitcnt vmcnt(6)" ::: "memory"); }
    else if (t+1 < nt) { asm volatile("s_waitcnt vmcnt(0)" ::: "memory"); }
    __builtin_amdgcn_s_barrier();
  }

  // ---- LDS-staged epilogue (bf16 out) ----
  {
    constexpr int ERS = 272;               // row stride in u16 (256 + 16 pad)
    u16* eb = lds_dyn;
    u16* dstb; long long rstride;
    if constexpr (MODE==1) { dstb = Cb + (long long)z*SL*SL + (long long)m0*SL + n0; rstride = SL; }
    else if constexpr (MODE==3) {
      int seg = n0 / 3072;                 // whole block lies in one segment (3072%256==0)
      u16* d0 = seg==0 ? Cb : (seg==1 ? Cb2 : Cb3);
      dstb = d0 + (long long)m0*3072 + (n0 - seg*3072); rstride = 3072;
    } else { dstb = Cb + (long long)m0*ldc + n0; rstride = ldc; }
    (void)Cf;
#pragma unroll
    for (int hf = 0; hf < 2; ++hf) {
      if (wr == hf) {
#pragma unroll
        for (int mi=0; mi<8; ++mi)
#pragma unroll
        for (int ni=0; ni<4; ++ni)
#pragma unroll
        for (int r=0; r<4; ++r) {
          int ml = mi*16 + ((lane>>4)<<2) + r;     // 0..127
          int nl = wc*64 + ni*16 + (lane & 15);
          float v = acc[mi][ni][r];
          if constexpr (EPI==2) {
            float u = 0.7978845608f*(v + 0.044715f*v*v*v);
            float th = 1.f - 2.f/(__expf(2.f*u)+1.f);
            v = 0.5f*v*(1.f + th);
          }
          if constexpr (EPI==3) v *= 0.0360843918f;  // 1/sqrt(768)
          int ch = nl >> 3, off = nl & 7;
          eb[ml*ERS + (((ch ^ ((ml>>2)&3)))<<3) + off] = f2b(v);
        }
      }
      __syncthreads();
#pragma unroll
      for (int j = 0; j < 8; ++j) {
        int c = tid + (j<<9);                      // 0..4095
        int row = c >> 5, nch = c & 31;
        u16x8 val = *(const u16x8*)(eb + row*ERS + (((nch ^ ((row>>2)&3)))<<3));
        *(u16x8*)(dstb + (long long)(hf*128 + row)*rstride + (nch<<3)) = val;
      }
      __syncthreads();
    }
  }
}

// ================= 256x128 8-phase BK=64 engine (MHA PV) =================
#define MFMA_Q(MB, NB, AF) \
  { _Pragma("unroll") for (int mi2=0; mi2<2; ++mi2) { \
      _Pragma("unroll") for (int ni2=0; ni2<2; ++ni2) { \
        acc[(MB)+mi2][(NB)+ni2] = __builtin_amdgcn_mfma_f32_16x16x32_bf16(AF[mi2][0], Bf[(NB)+ni2][0], acc[(MB)+mi2][(NB)+ni2], 0,0,0); \
        acc[(MB)+mi2][(NB)+ni2] = __builtin_amdgcn_mfma_f32_16x16x32_bf16(AF[mi2][1], Bf[(NB)+ni2][1], acc[(MB)+mi2][(NB)+ni2], 0,0,0); } } }

__global__ __launch_bounds__(512,2) void gemm128n_k(
    const u16* __restrict__ A, const u16* __restrict__ Bt, u16* __restrict__ Cb, int K)
{
  extern __shared__ u16 lds_dyn[];           // A [2][256][64] @0 | B [2][128][64] @32768
  const int tid = threadIdx.x, lane = tid & 63, wv = tid >> 6;
  const int wr = wv >> 1, wc = wv & 1;
  const int m0 = blockIdx.x * 256, n0 = blockIdx.y * 128, z = blockIdx.z;
  const int bb = z >> 2, hh = z & 3;
  const long long baseA = (long long)z*SL*SL;
  const long long baseB = ((long long)bb*3072 + hh*DKM)*SL;
  const int nt = K >> 6;

  const int rb = (wv*64 + lane) >> 3;
  const int sg = ((lane & 7) ^ (rb & 7)) * 8;
  const int rd0 = (lane & 15)*64 + (((lane>>4) ^ (lane & 7)) * 8);
  const int rd1 = rd0 ^ 32;

  auto stageA = [&](int buf, int half, int kt) {
#pragma unroll
    for (int tt = 0; tt < 2; ++tt) {
      const int t = half*2 + tt;             // contiguous: h0 rows [0,128) == phase mh0 reads
      gld16(lds_dyn + buf*16384 + t*4096 + wv*512,
            A + baseA + (long long)(m0 + t*64 + rb)*SL + (long long)kt*64 + sg);
    }
  };
  auto stageB = [&](int buf, int idx, int kt) {
    gld16(lds_dyn + 32768 + buf*8192 + idx*4096 + wv*512,
          Bt + baseB + (long long)(n0 + idx*64 + rb)*SL + (long long)kt*64 + sg);
  };

  f32x4 acc[4][4] = {};
  bf16x8 Af[2][2];
  bf16x8 Bf[4][2];

  stageA(0,0,0); stageB(0,0,0); stageB(0,1,0); stageA(0,1,0);
  stageA(1,0,1); stageB(1,0,1); stageB(1,1,1);
  asm volatile("s_waitcnt vmcnt(4)" ::: "memory");
  __builtin_amdgcn_s_barrier();

  for (int t = 0; t < nt; ++t) {
    const int d = t & 1;
    const u16* As_d = lds_dyn + d*16384;
    const u16* Bs_d = lds_dyn + 32768 + d*8192;
#pragma unroll
    for (int mi2=0; mi2<2; ++mi2) {
      const u16* p = As_d + (wr*32 + mi2*16)*64;
      Af[mi2][0] = *(const bf16x8*)(p + rd0);
      Af[mi2][1] = *(const bf16x8*)(p + rd1);
    }
#pragma unroll
    for (int ni2=0; ni2<2; ++ni2) {
      const u16* p = Bs_d + (wc*64 + ni2*16)*64;
      Bf[ni2][0] = *(const bf16x8*)(p + rd0);
      Bf[ni2][1] = *(const bf16x8*)(p + rd1);
    }
    if (t+1 < nt) stageA(d^1, 1, t+1);
    PHASE_SYNC; MFMA_Q(0,0,Af); PHASE_END;
#pragma unroll
    for (int ni2=0; ni2<2; ++ni2) {
      const u16* p = Bs_d + (wc*64 + 32 + ni2*16)*64;
      Bf[2+ni2][0] = *(const bf16x8*)(p + rd0);
      Bf[2+ni2][1] = *(const bf16x8*)(p + rd1);
    }
    if (t+2 < nt) stageA(d, 0, t+2);
    PHASE_SYNC; MFMA_Q(0,2,Af); PHASE_END;
#pragma unroll
    for (int mi2=0; mi2<2; ++mi2) {
      const u16* p = As_d + (128 + wr*32 + mi2*16)*64;
      Af[mi2][0] = *(const bf16x8*)(p + rd0);
      Af[mi2][1] = *(const bf16x8*)(p + rd1);
    }
    if (t+2 < nt) stageB(d, 0, t+2);
    PHASE_SYNC; MFMA_Q(2,0,Af); PHASE_END;
    if (t+2 < nt) stageB(d, 1, t+2);
    __builtin_amdgcn_s_barrier();
    __builtin_amdgcn_s_setprio(1);
    MFMA_Q(2,2,Af);
    __builtin_amdgcn_s_setprio(0);
    if (t+2 < nt)      { asm volatile("s_waitcnt vmcnt(4)" ::: "memory"); }
    else if (t+1 < nt) { asm volatile("s_waitcnt vmcnt(0)" ::: "memory"); }
    __builtin_amdgcn_s_barrier();
  }

  // ---- LDS-staged epilogue ----
  {
    constexpr int ERS = 136;               // 128 + 8 pad u16
    u16* eb = lds_dyn;
    u16* dstb = Cb + ((long long)bb*SL + m0)*3072 + hh*DKM + n0;
#pragma unroll
    for (int hf = 0; hf < 2; ++hf) {
#pragma unroll
      for (int mi2=0; mi2<2; ++mi2) {
        const int mi = hf*2 + mi2;         // (mi>>1) == hf
#pragma unroll
        for (int ni=0; ni<4; ++ni)
#pragma unroll
        for (int r=0; r<4; ++r) {
          int ml = wr*32 + (mi&1)*16 + ((lane>>4)<<2) + r;   // 0..127
          int nl = wc*64 + ni*16 + (lane & 15);
          int ch = nl >> 3, off = nl & 7;
          eb[ml*ERS + (((ch ^ ((ml>>2)&3)))<<3) + off] = f2b(acc[mi][ni][r]);
        }
      }
      __syncthreads();
#pragma unroll
      for (int j = 0; j < 4; ++j) {
        int c = tid + (j<<9);                      // 0..2047
        int row = c >> 4, nch = c & 15;
        u16x8 val = *(const u16x8*)(eb + row*ERS + (((nch ^ ((row>>2)&3)))<<3));
        *(u16x8*)(dstb + (long long)(hf*128 + row)*3072 + (nch<<3)) = val;
      }
      __syncthreads();
    }
  }
}

// ---------------- legacy 128x128 BK=32 GEMM ----------------
// MODE 0: dense.  5: 3-way col scatter (768 segs).
template<int BM, int BN, int MODE, int EPI>
__global__ __launch_bounds__(256) void gemm_k(
    const u16* __restrict__ A, const u16* __restrict__ Bt,
    float* __restrict__ Cf, u16* __restrict__ Cb,
    u16* __restrict__ Cb2, u16* __restrict__ Cb3,
    int K, int lda, int ldb, int ldc)
{
  constexpr int BK = 32;
  constexpr int WM = BM/2, WN = BN/2, FM = WM/16, FN = WN/16;
  __shared__ __attribute__((aligned(16))) u16 As[BM*BK];
  __shared__ __attribute__((aligned(16))) u16 Bs[BN*BK];
  const int tid = threadIdx.x, lane = tid & 63, wv = tid >> 6;
  const int wr = wv >> 1, wc = wv & 1;
  const int m0 = blockIdx.x * BM, n0 = blockIdx.y * BN;

  f32x4 acc[FM][FN] = {};

  for (int kt = 0; kt < K; kt += BK) {
#pragma unroll
    for (int t = 0; t < (BM*4)/256; ++t) {
      int cb  = (t*4 + wv)*64;
      int ch  = cb + lane;
      int row = ch >> 2, cp = ch & 3;
      int gp  = cp ^ (row & 3) ^ ((row >> 2) & 1);
      long long ga = (long long)(m0 + row)*lda + (kt + gp*8);
      gld16(&As[cb*8], A + ga);
    }
#pragma unroll
    for (int t = 0; t < (BN*4)/256; ++t) {
      int cb  = (t*4 + wv)*64;
      int ch  = cb + lane;
      int row = ch >> 2, cp = ch & 3;
      int gp  = cp ^ (row & 3) ^ ((row >> 2) & 1);
      long long gb = (long long)(n0 + row)*ldb + (kt + gp*8);
      gld16(&Bs[cb*8], Bt + gb);
    }
    __syncthreads();
    bf16x8 af[FM], bfr[FN];
#pragma unroll
    for (int mi=0; mi<FM; ++mi) {
      int row = wr*WM + mi*16 + (lane & 15);
      int cp  = (lane >> 4) ^ (row & 3) ^ ((row >> 2) & 1);
      af[mi] = *reinterpret_cast<const bf16x8*>(&As[row*BK + cp*8]);
    }
#pragma unroll
    for (int ni=0; ni<FN; ++ni) {
      int row = wc*WN + ni*16 + (lane & 15);
      int cp  = (lane >> 4) ^ (row & 3) ^ ((row >> 2) & 1);
      bfr[ni] = *reinterpret_cast<const bf16x8*>(&Bs[row*BK + cp*8]);
    }
#pragma unroll
    for (int mi=0; mi<FM; ++mi)
#pragma unroll
      for (int ni=0; ni<FN; ++ni)
        acc[mi][ni] = __builtin_amdgcn_mfma_f32_16x16x32_bf16(af[mi], bfr[ni], acc[mi][ni], 0,0,0);
    __syncthreads();
  }

#pragma unroll
  for (int mi=0; mi<FM; ++mi)
#pragma unroll
  for (int ni=0; ni<FN; ++ni)
#pragma unroll
  for (int r=0; r<4; ++r) {
    int m = m0 + wr*WM + mi*16 + ((lane>>4)<<2) + r;
    int n = n0 + wc*WN + ni*16 + (lane & 15);
    float v = acc[mi][ni][r];
    if constexpr (MODE==5) {
      int seg = n / 768, nn = n - seg*768;
      u16* dst = seg==0 ? Cb : (seg==1 ? Cb2 : Cb3);
      dst[(long long)m*768 + nn] = f2b(v);
    } else {
      long long ci = (long long)m*ldc + n;
      if constexpr (EPI==0) Cf[ci] = v; else Cb[ci] = f2b(v);
    }
  }
}

// ================= fused sliding-window attention =================
__global__ __launch_bounds__(256) void sw_attn_k(
    const u16* __restrict__ Qm, const u16* __restrict__ Km,
    const u16* __restrict__ Vt, u16* __restrict__ Om)
{
  __shared__ __attribute__((aligned(16))) u16 Kb_s[64*64];
  __shared__ __attribute__((aligned(16))) u16 Vb_s[64*64];
  __shared__ __attribute__((aligned(16))) u16 Pb_s[4*32*64];
  const int tid = threadIdx.x, lane = tid & 63, wv = tid >> 6;
  const int qc = blockIdx.x >> 1, half = blockIdx.x & 1;
  const int h = blockIdx.y, b = blockIdx.z;
  const int q0 = qc*256 + half*128 + wv*32;
  const long long rowbase = (long long)b*SL;

  bf16x8 Qf[2][2];
#pragma unroll
  for (int mi=0;mi<2;++mi)
#pragma unroll
    for (int ks=0;ks<2;++ks)
      Qf[mi][ks] = *(const bf16x8*)(Qm + (rowbase + q0 + mi*16 + (lane&15))*DM + h*DH + ks*32 + (lane>>4)*8);

  f32x4 accO[2][4] = {};
  float mrun[2][4], lrun[2][4];
#pragma unroll
  for (int mi=0;mi<2;++mi)
#pragma unroll
    for (int r=0;r<4;++r){ mrun[mi][r]=-3e38f; lrun[mi][r]=0.f; }

  const int srow = tid >> 3;
  const int schunk = (tid & 7) ^ (srow & 7);

  const int kb0 = qc*256 + half*128 - 256;
  const int slo = kb0 < 0 ? ((-kb0) >> 6) : 0;
  const int shi_t = (SL - kb0) >> 6;
  const int shi = shi_t < 10 ? shi_t : 10;

  const int qpb = q0 + ((lane>>4)<<2);

  for (int s = slo; s < shi; ++s) {
    const int kb = kb0 + s*64;
#pragma unroll
    for (int ii=0; ii<2; ++ii) {
      gld16(Kb_s + ii*2048 + wv*512,
            Km + (rowbase + kb + srow + ii*32)*DM + h*DH + schunk*8);
      gld16(Vb_s + ii*2048 + wv*512,
            Vt + ((long long)b*DM + h*DH + srow + ii*32)*SL + kb + schunk*8);
    }
    asm volatile("s_waitcnt vmcnt(0)" ::: "memory");
    __syncthreads();

    f32x4 accS[2][4] = {};
    {
      bf16x8 Kf[4][2];
#pragma unroll
      for (int nf=0;nf<4;++nf){
        int row = nf*16 + (lane&15);
#pragma unroll
        for (int ks=0;ks<2;++ks){
          int ch = ((lane>>4) + ks*4) ^ (row&7);
          Kf[nf][ks] = *(const bf16x8*)(Kb_s + row*64 + ch*8);
        }
      }
#pragma unroll
      for (int mi=0;mi<2;++mi)
#pragma unroll
        for (int nf=0;nf<4;++nf){
          accS[mi][nf] = __builtin_amdgcn_mfma_f32_16x16x32_bf16(Qf[mi][0], Kf[nf][0], accS[mi][nf], 0,0,0);
          accS[mi][nf] = __builtin_amdgcn_mfma_f32_16x16x32_bf16(Qf[mi][1], Kf[nf][1], accS[mi][nf], 0,0,0);
        }
    }

    float smax[2][4];
#pragma unroll
    for (int mi=0;mi<2;++mi)
#pragma unroll
      for (int r=0;r<4;++r) smax[mi][r] = -3e38f;
#pragma unroll
    for (int mi=0;mi<2;++mi)
#pragma unroll
      for (int nf=0;nf<4;++nf)
#pragma unroll
        for (int r=0;r<4;++r){
          int dd = (kb + nf*16 + (lane&15)) - (qpb + mi*16 + r);
          bool ok = (dd <= 256) && (dd >= -256);
          float v = ok ? accS[mi][nf][r]*0.125f : -3e38f;
          accS[mi][nf][r] = v;
          smax[mi][r] = fmaxf(smax[mi][r], v);
        }
#pragma unroll
    for (int mi=0;mi<2;++mi)
#pragma unroll
      for (int r=0;r<4;++r){
        float v = smax[mi][r];
        v = fmaxf(v, __shfl_xor(v,1,64)); v = fmaxf(v, __shfl_xor(v,2,64));
        v = fmaxf(v, __shfl_xor(v,4,64)); v = fmaxf(v, __shfl_xor(v,8,64));
        smax[mi][r] = v;
      }

#pragma unroll
    for (int mi=0;mi<2;++mi)
#pragma unroll
      for (int r=0;r<4;++r){
        float mn = fmaxf(mrun[mi][r], smax[mi][r]);
        float sc = __expf(mrun[mi][r] - mn);
        float ls = 0.f;
#pragma unroll
        for (int nf=0;nf<4;++nf){
          float sv = accS[mi][nf][r];
          float p = (sv > -1e37f) ? __expf(sv - mn) : 0.f;
          accS[mi][nf][r] = p;
          ls += p;
        }
        ls += __shfl_xor(ls,1,64); ls += __shfl_xor(ls,2,64);
        ls += __shfl_xor(ls,4,64); ls += __shfl_xor(ls,8,64);
        lrun[mi][r] = lrun[mi][r]*sc + ls;
        mrun[mi][r] = mn;
#pragma unroll
        for (int df=0;df<4;++df) accO[mi][df][r] *= sc;
      }
#pragma unroll
    for (int mi=0;mi<2;++mi)
#pragma unroll
      for (int nf=0;nf<4;++nf)
#pragma unroll
        for (int r=0;r<4;++r){
          int ql = mi*16 + ((lane>>4)<<2) + r;
          int k  = nf*16 + (lane&15);
          int ch = (k>>3) ^ (ql&7);
          Pb_s[wv*2048 + ql*64 + ch*8 + (k&7)] = f2b(accS[mi][nf][r]);
        }
    asm volatile("s_waitcnt lgkmcnt(0)" ::: "memory");
    __builtin_amdgcn_sched_barrier(0);

    {
      bf16x8 Pf[2][2], Vf[4][2];
#pragma unroll
      for (int mi=0;mi<2;++mi){
        int ql = mi*16 + (lane&15);
#pragma unroll
        for (int ks=0;ks<2;++ks){
          int ch = ((lane>>4) + ks*4) ^ (ql&7);
          Pf[mi][ks] = *(const bf16x8*)(Pb_s + wv*2048 + ql*64 + ch*8);
        }
      }
#pragma unroll
      for (int df=0;df<4;++df){
        int dr = df*16 + (lane&15);
#pragma unroll
        for (int ks=0;ks<2;++ks){
          int ch = ((lane>>4) + ks*4) ^ (dr&7);
          Vf[df][ks] = *(const bf16x8*)(Vb_s + dr*64 + ch*8);
        }
      }
#pragma unroll
      for (int mi=0;mi<2;++mi)
#pragma unroll
        for (int df=0;df<4;++df){
          accO[mi][df] = __builtin_amdgcn_mfma_f32_16x16x32_bf16(Pf[mi][0], Vf[df][0], accO[mi][df], 0,0,0);
          accO[mi][df] = __builtin_amdgcn_mfma_f32_16x16x32_bf16(Pf[mi][1], Vf[df][1], accO[mi][df], 0,0,0);
        }
    }
    __syncthreads();
  }

#pragma unroll
  for (int mi=0;mi<2;++mi)
#pragma unroll
    for (int df=0;df<4;++df)
#pragma unroll
      for (int r=0;r<4;++r){
        long long row = rowbase + qpb + mi*16 + r;
        int col = h*DH + df*16 + (lane&15);
        Om[row*DM + col] = f2b(accO[mi][df][r] / lrun[mi][r]);
      }
}

// ---------------- pointwise / small kernels ----------------
__global__ __launch_bounds__(256) void embed_ln_k(const int* __restrict__ x,
    const float* __restrict__ emb, const float* __restrict__ pos,
    const float* __restrict__ g, const float* __restrict__ bta,
    float* __restrict__ of, u16* __restrict__ ob)
{
  __shared__ float sm[4];
  const int row = blockIdx.x, s = row & (SL-1);
  const long long tok = x[row];
  const float* e = emb + tok*DM;
  const float* p = pos + (long long)s*DM;
  float v[3], su=0.f, sq=0.f;
#pragma unroll
  for (int i=0;i<3;++i){ int d=threadIdx.x+i*256; v[i]=e[d]+p[d]; su+=v[i]; sq+=v[i]*v[i]; }
  su = bred_sum(su, sm); sq = bred_sum(sq, sm);
  float mean = su*(1.f/DM), var = sq*(1.f/DM)-mean*mean, rs = rsqrtf(var+1e-5f);
#pragma unroll
  for (int i=0;i<3;++i){ int d=threadIdx.x+i*256;
    float o = (v[i]-mean)*rs*g[d] + bta[d];
    of[(long long)row*DM+d]=o; ob[(long long)row*DM+d]=f2b(o); }
}

// a + c -> LN
__global__ __launch_bounds__(256) void resid_ln_k(const float* __restrict__ a, const float* __restrict__ c,
    const float* __restrict__ g, const float* __restrict__ bta,
    float* __restrict__ of, u16* __restrict__ ob)
{
  __shared__ float sm[4];
  const long long row = blockIdx.x;
  const float* ra = a + row*DM;
  const float* rc = c + row*DM;
  float v[3], su=0.f, sq=0.f;
#pragma unroll
  for (int i=0;i<3;++i){
    int d=threadIdx.x+i*256;
    v[i]=ra[d]+rc[d];
    su+=v[i]; sq+=v[i]*v[i];
  }
  su = bred_sum(su, sm); sq = bred_sum(sq, sm);
  float mean = su*(1.f/DM), var = sq*(1.f/DM)-mean*mean, rs = rsqrtf(var+1e-5f);
#pragma unroll
  for (int i=0;i<3;++i){ int d=threadIdx.x+i*256;
    float o = (v[i]-mean)*rs*g[d] + bta[d];
    of[row*DM+d]=o; if (ob) ob[row*DM+d]=f2b(o); }
}

// fp32 [Kd,Nd] -> bf16 [Nd,Kd]; 64x64 tiles, float4 loads, 8B bf16 writes
__global__ __launch_bounds__(256) void transp_w_k(const float* __restrict__ W, u16* __restrict__ Wt, int Kd, int Nd)
{
  __shared__ float t[64][65];
  int n0 = blockIdx.x*64, k0 = blockIdx.y*64;
  int lx = threadIdx.x & 15, ly = threadIdx.x >> 4;
#pragma unroll
  for (int i=0;i<4;++i){
    const float4 v = *(const float4*)(W + (long long)(k0+ly+i*16)*Nd + n0 + lx*4);
    t[ly+i*16][lx*4+0]=v.x; t[ly+i*16][lx*4+1]=v.y; t[ly+i*16][lx*4+2]=v.z; t[ly+i*16][lx*4+3]=v.w;
  }
  __syncthreads();
#pragma unroll
  for (int i=0;i<4;++i){
    int nn = ly + i*16, kk = lx*4;
    u16x4 o = { f2b(t[kk][nn]), f2b(t[kk+1][nn]), f2b(t[kk+2][nn]), f2b(t[kk+3][nn]) };
    *(u16x4*)(Wt + (long long)(n0+nn)*Kd + k0 + kk) = o;
  }
}

// bf16 [8192,Nc] -> bf16 [B][Nc][SL]
__global__ __launch_bounds__(256) void transp_b_k(const u16* __restrict__ in, u16* __restrict__ out, int Nc)
{
  __shared__ u16 t[32][33];
  int c0 = blockIdx.x*32, r0 = blockIdx.y*32;
  int lx = threadIdx.x & 31, ly = threadIdx.x >> 5;
#pragma unroll
  for (int i=0;i<4;++i) t[ly+i*8][lx] = in[(long long)(r0+ly+i*8)*Nc + c0+lx];
  __syncthreads();
  int b = r0 >> 11, s0 = r0 & (SL-1);
#pragma unroll
  for (int i=0;i<4;++i) out[((long long)b*Nc + c0+ly+i*8)*SL + s0+lx] = t[lx][ly+i*8];
}

// outer-MHA softmax: one wave per row, in-place on pre-scaled bf16 scores
__global__ __launch_bounds__(256) void mha_softmax_k(u16* __restrict__ sc, const int* __restrict__ x)
{
  const int r = blockIdx.x*4 + (threadIdx.x >> 6);
  const int lane = threadIdx.x & 63;
  const int z = r >> 11;
  const int b = z >> 2;
  u16* row = sc + (long long)z*SL*SL + (long long)(r & (SL-1))*SL;
  const int* xb = x + b*SL;
  float v[32]; float mx = -3e38f;
#pragma unroll
  for (int i=0;i<4;++i){
    const int j0 = i*512 + lane*8;
    u16x8 pv = *(const u16x8*)(row + j0);
    i32x4 xa = *(const i32x4*)(xb + j0);
    i32x4 xc = *(const i32x4*)(xb + j0 + 4);
#pragma unroll
    for (int e=0;e<8;++e){
      int xv = e<4 ? xa[e] : xc[e-4];
      float f = (xv != 0) ? b2f(pv[e]) : -3e38f;
      v[i*8+e] = f;
      mx = fmaxf(mx, f);
    }
  }
  mx = wred_max(mx);
  float s = 0.f;
#pragma unroll
  for (int i=0;i<32;++i){ v[i] = (v[i] > -1e37f) ? __expf(v[i]-mx) : 0.f; s += v[i]; }
  s = wred_sum(s);
  float inv = 1.f/s;
#pragma unroll
  for (int i=0;i<4;++i){
    u16x8 ov;
#pragma unroll
    for (int e=0;e<8;++e) ov[e] = f2b(v[i*8+e]*inv);
    *(u16x8*)(row + i*512 + lane*8) = ov;
  }
}

__global__ __launch_bounds__(256) void pool_part_k(const float* __restrict__ f, float* __restrict__ pp)
{
  int b = blockIdx.x, ch = blockIdx.y;
  float m0=-3e38f, m1=-3e38f, m2=-3e38f;
  for (int s = ch*32; s < ch*32+32; ++s){
    const float* r = f + ((long long)b*SL + s)*DM;
    m0=fmaxf(m0,r[threadIdx.x]); m1=fmaxf(m1,r[threadIdx.x+256]); m2=fmaxf(m2,r[threadIdx.x+512]);
  }
  float* o = pp + (long long)(b*64+ch)*DM;
  o[threadIdx.x]=m0; o[threadIdx.x+256]=m1; o[threadIdx.x+512]=m2;
}

__global__ __launch_bounds__(256) void pool_red_k(const float* __restrict__ pp, float* __restrict__ out)
{
  int b = blockIdx.x;
#pragma unroll
  for (int i=0;i<3;++i){
    int d = threadIdx.x + i*256;
    float m = -3e38f;
    for (int c=0;c<64;++c) m = fmaxf(m, pp[(long long)(b*64+c)*DM + d]);
    out[(long long)b*DM + d] = m;
  }
}

// ---------------- orchestration ----------------
extern "C" void kernel_launch(void* const* d_in, const int* in_sizes, int n_in,
                              void* d_out, int out_size, void* d_ws, size_t ws_size,
                              hipStream_t stream)
{
  const int*   x      = (const int*)  d_in[0];
  const float* emb    = (const float*)d_in[1];
  const float* pos    = (const float*)d_in[2];
  const float* ln_e_g = (const float*)d_in[3];
  const float* ln_e_b = (const float*)d_in[4];
  const float* lf_wq  = (const float*)d_in[5];
  const float* lf_wk  = (const float*)d_in[6];
  const float* lf_wv  = (const float*)d_in[7];
  const float* lf_wo  = (const float*)d_in[8];
  const float* ln1_g  = (const float*)d_in[9];
  const float* ln1_b  = (const float*)d_in[10];
  const float* w1     = (const float*)d_in[11];
  const float* w2     = (const float*)d_in[12];
  const float* ln2_g  = (const float*)d_in[13];
  const float* ln2_b  = (const float*)d_in[14];
  const float* mha_wq = (const float*)d_in[15];
  const float* mha_wk = (const float*)d_in[16];
  const float* mha_wv = (const float*)d_in[17];
  const float* mha_fc = (const float*)d_in[18];
  const float* mha_ln_g = (const float*)d_in[19];
  const float* mha_ln_b = (const float*)d_in[20];

  (void)hipFuncSetAttribute((const void*)gemm256_k<0,2>, hipFuncAttributeMaxDynamicSharedMemorySize, 131072);
  (void)hipFuncSetAttribute((const void*)gemm256_k<1,3>, hipFuncAttributeMaxDynamicSharedMemorySize, 131072);
  (void)hipFuncSetAttribute((const void*)gemm256_k<3,1>, hipFuncAttributeMaxDynamicSharedMemorySize, 131072);
  (void)hipFuncSetAttribute((const void*)gemm128n_k,     hipFuncAttributeMaxDynamicSharedMemorySize, 98304);

  const long long R = 8192;           // B*S rows
  float* F0 = (float*)d_ws;           // h / out_lf (fp32)
  float* F1 = F0 + R*DM;              // gemm fp32 out
  float* F2 = F1 + R*DM;              // h2 / final ln
  u16* B0 = (u16*)(F2 + R*DM);        // h bf16 -> attn-out bf16
  u16* B1 = B0 + R*DM;                // lf q -> h2 bf16
  u16* B2 = B1 + R*DM;                // lf k -> out_lf bf16
  u16* B3 = B2 + R*DM;                // lf v^T [B][768][SL]
  u16* WT = B3 + R*DM;                // transposed weights (bf16, up to 9216x768)
  u16* G1 = WT + (long long)9216*DM;  // gelu-out / mha q
  u16* G2 = G1 + R*DFF;               // mha k -> mha o
  u16* G3 = G2 + R*DFF;               // mha v^T [B][3072][SL]
  u16* SC = G3 + R*DFF;               // lf/mha v temp, mha P (134MB)
  float* PP = (float*)(SC + (long long)16*SL*SL);   // pool partials (4x64x768)

  dim3 T(256), T5(512);
  const size_t SM256 = 131072, SM128 = 98304;

  // ---- longformer layer
  embed_ln_k<<<dim3(8192), T, 0, stream>>>(x, emb, pos, ln_e_g, ln_e_b, F0, B0);

  // fused lf qkv: WT = [q|k|v]^T (2304x768), scatter -> B1,B2,SC
  transp_w_k<<<dim3(12,12), T, 0, stream>>>(lf_wq, WT,               DM, DM);
  transp_w_k<<<dim3(12,12), T, 0, stream>>>(lf_wk, WT + 768*768,     DM, DM);
  transp_w_k<<<dim3(12,12), T, 0, stream>>>(lf_wv, WT + 2*768*768,   DM, DM);
  gemm_k<128,128,5,1><<<dim3(64,18), T, 0, stream>>>(B0, WT, nullptr, B1, B2, SC, DM, DM, DM, 0);
  transp_b_k<<<dim3(24,256), T, 0, stream>>>(SC, B3, DM);

  sw_attn_k<<<dim3(16,12,4), T, 0, stream>>>(B1, B2, B3, B0);

  transp_w_k<<<dim3(12,12), T, 0, stream>>>(lf_wo, WT, DM, DM);
  gemm_k<128,128,0,0><<<dim3(64,6), T, 0, stream>>>(B0, WT, F1, nullptr, nullptr, nullptr, DM, DM, DM, DM);
  resid_ln_k<<<dim3(8192), T, 0, stream>>>(F0, F1, ln1_g, ln1_b, F2, B1);

  transp_w_k<<<dim3(48,12), T, 0, stream>>>(w1, WT, DM, DFF);
  gemm256_k<0,2><<<dim3(32,12,1), T5, SM256, stream>>>(B1, WT, nullptr, G1, nullptr, nullptr, DM, DM, DM, DFF);
  transp_w_k<<<dim3(12,48), T, 0, stream>>>(w2, WT, DFF, DM);
  gemm_k<128,128,0,0><<<dim3(64,6), T, 0, stream>>>(G1, WT, F1, nullptr, nullptr, nullptr, DFF, DFF, DFF, DM);
  resid_ln_k<<<dim3(8192), T, 0, stream>>>(F2, F1, ln2_g, ln2_b, F0, B2);

  // ---- outer MHA: fused qkv (WT = [wq|wk|wv]^T 9216x768), scatter -> G1,G2,SC
  transp_w_k<<<dim3(48,12), T, 0, stream>>>(mha_wq, WT,                 DM, DFF);
  transp_w_k<<<dim3(48,12), T, 0, stream>>>(mha_wk, WT + (long long)3072*768, DM, DFF);
  transp_w_k<<<dim3(48,12), T, 0, stream>>>(mha_wv, WT + (long long)6144*768, DM, DFF);
  gemm256_k<3,1><<<dim3(32,36,1), T5, SM256, stream>>>(B2, WT, nullptr, G1, G2, SC, DM, DM, DM, 3072);
  transp_b_k<<<dim3(96,256), T, 0, stream>>>(SC, G3, DFF);

  gemm256_k<1,3><<<dim3(8,8,16), T5, SM256, stream>>>(G1, G2, nullptr, SC, nullptr, nullptr, DKM, 3072, 3072, SL);
  mha_softmax_k<<<dim3(8192), T, 0, stream>>>(SC, x);
  gemm128n_k<<<dim3(8,6,16), T5, SM128, stream>>>(SC, G3, G2, SL);

  transp_w_k<<<dim3(12,48), T, 0, stream>>>(mha_fc, WT, DFF, DM);
  gemm_k<128,128,0,0><<<dim3(64,6), T, 0, stream>>>(G2, WT, F1, nullptr, nullptr, nullptr, DFF, DFF, DFF, DM);
  resid_ln_k<<<dim3(8192), T, 0, stream>>>(F0, F1, mha_ln_g, mha_ln_b, F2, nullptr);

  pool_part_k<<<dim3(4,64), T, 0, stream>>>(F2, PP);
  pool_red_k<<<dim3(4), T, 0, stream>>>(PP, (float*)d_out);
}

// Round 11
// 941.147 us; speedup vs baseline: 1.0321x; 1.0321x over previous
//
#include <hip/hip_runtime.h>
#include <hip/hip_bf16.h>
#include <math.h>

#define DEV static __device__ __forceinline__

typedef unsigned short u16;
typedef __attribute__((ext_vector_type(8))) __bf16 bf16x8;
typedef __attribute__((ext_vector_type(8))) unsigned short u16x8;
typedef __attribute__((ext_vector_type(4))) float f32x4;
typedef __attribute__((ext_vector_type(4))) int i32x4;

constexpr int SL  = 2048;   // seq len
constexpr int DM  = 768;    // d_model
constexpr int DH  = 64;     // longformer head dim
constexpr int DFF = 3072;
constexpr int DKM = 768;    // outer-MHA head dim

DEV float b2f(u16 u){ union{float f; unsigned u;} c; c.u = ((unsigned)u)<<16; return c.f; }
DEV u16 f2b(float f){ union{float f; unsigned u;} c; c.f=f; unsigned r=(c.u + 0x7fffu + ((c.u>>16)&1u))>>16; return (u16)r; }

DEV void gld16(u16* lds, const u16* g){
  __builtin_amdgcn_global_load_lds((const __attribute__((address_space(1))) void*)g,
                                   (__attribute__((address_space(3))) void*)lds, 16, 0, 0);
}

// ---------------- reductions ----------------
DEV float wred_sum(float v){
#pragma unroll
  for (int o=32;o;o>>=1) v += __shfl_xor(v,o,64);
  return v;
}
DEV float wred_max(float v){
#pragma unroll
  for (int o=32;o;o>>=1) v = fmaxf(v, __shfl_xor(v,o,64));
  return v;
}
DEV float bred_sum(float v, float* sm){
  v = wred_sum(v);
  if ((threadIdx.x & 63)==0) sm[threadIdx.x>>6] = v;
  __syncthreads();
  float r = sm[0]+sm[1]+sm[2]+sm[3];
  __syncthreads();
  return r;
}

#define PHASE_SYNC \
  __builtin_amdgcn_s_barrier(); \
  asm volatile("s_waitcnt lgkmcnt(0)" ::: "memory"); \
  __builtin_amdgcn_sched_barrier(0); \
  __builtin_amdgcn_s_setprio(1);
#define PHASE_END \
  __builtin_amdgcn_s_setprio(0); \
  __builtin_amdgcn_s_barrier();

// ================= 256x256 8-phase BK=64 MFMA GEMM =================
// C = A[M,K] * Bt[N,K]^T, fp32 accum, bf16 inputs.
// MODE 0: dense.  1: MHA scores (z=(b,h)).  3: 3-way col scatter (3072 segs).
// EPI 0: fp32. 1: bf16. 2: fast-gelu+bf16. 3: *1/sqrt(768)+bf16.
#define MFMA_PH(MH, NH) \
  { _Pragma("unroll") for (int mi2=0; mi2<4; ++mi2) { \
      _Pragma("unroll") for (int ni2=0; ni2<2; ++ni2) { \
        acc[(MH)*4+mi2][(NH)*2+ni2] = __builtin_amdgcn_mfma_f32_16x16x32_bf16(Af[mi2][0], Bf[(NH)*2+ni2][0], acc[(MH)*4+mi2][(NH)*2+ni2], 0,0,0); \
        acc[(MH)*4+mi2][(NH)*2+ni2] = __builtin_amdgcn_mfma_f32_16x16x32_bf16(Af[mi2][1], Bf[(NH)*2+ni2][1], acc[(MH)*4+mi2][(NH)*2+ni2], 0,0,0); } } }

template<int MODE, int EPI>
__global__ __launch_bounds__(512,2) void gemm256_k(
    const u16* __restrict__ A, const u16* __restrict__ Bt,
    float* __restrict__ Cf, u16* __restrict__ Cb,
    u16* __restrict__ Cb2, u16* __restrict__ Cb3,
    int K, int lda, int ldb, int ldc)
{
  extern __shared__ u16 lds_dyn[];           // [2][256][64] A | [2][256][64] B
  const int tid = threadIdx.x, lane = tid & 63, wv = tid >> 6;
  const int wr = wv >> 2, wc = wv & 3;
  const int m0 = blockIdx.x * 256, n0 = blockIdx.y * 256, z = blockIdx.z;
  const int nt = K >> 6;

  int bb = 0, hh = 0;
  long long baseA = 0, baseB = 0;
  if constexpr (MODE==1) { bb=z>>2; hh=z&3; baseA=(long long)bb*SL*3072 + hh*DKM; baseB=baseA; }

  const int rb = (wv*64 + lane) >> 3;
  const int sg = ((lane & 7) ^ (rb & 7)) * 8;
  const int rd0 = (lane & 15)*64 + (((lane>>4) ^ (lane & 7)) * 8);
  const int rd1 = rd0 ^ 32;

  auto stageA = [&](int buf, int half, int kt) {
#pragma unroll
    for (int tt = 0; tt < 2; ++tt) {
      const int t = half + tt*2;             // INTERLEAVED halves: h0={0,2}, h1={1,3}
      gld16(lds_dyn + buf*16384 + t*4096 + wv*512,
            A + baseA + (long long)(m0 + t*64 + rb)*lda + (long long)kt*64 + sg);
    }
  };
  auto stageB = [&](int buf, int half, int kt) {
#pragma unroll
    for (int tt = 0; tt < 2; ++tt) {
      const int t = half*2 + tt;             // contiguous (all B reads finish by end of Q1)
      gld16(lds_dyn + 32768 + buf*16384 + t*4096 + wv*512,
            Bt + baseB + (long long)(n0 + t*64 + rb)*ldb + (long long)kt*64 + sg);
    }
  };

  f32x4 acc[8][4] = {};
  bf16x8 Af[4][2];
  bf16x8 Bf[4][2];

  stageA(0,0,0); stageB(0,0,0); stageB(0,1,0); stageA(0,1,0);
  stageA(1,0,1); stageB(1,0,1); stageB(1,1,1);
  asm volatile("s_waitcnt vmcnt(6)" ::: "memory");
  __builtin_amdgcn_s_barrier();

  for (int t = 0; t < nt; ++t) {
    const int d = t & 1;
    const u16* As_d = lds_dyn + d*16384;
    const u16* Bs_d = lds_dyn + 32768 + d*16384;
#pragma unroll
    for (int mi2=0; mi2<4; ++mi2) {
      const u16* p = As_d + (wr*128 + mi2*16)*64;
      Af[mi2][0] = *(const bf16x8*)(p + rd0);
      Af[mi2][1] = *(const bf16x8*)(p + rd1);
    }
#pragma unroll
    for (int ni2=0; ni2<2; ++ni2) {
      const u16* p = Bs_d + (wc*64 + ni2*16)*64;
      Bf[ni2][0] = *(const bf16x8*)(p + rd0);
      Bf[ni2][1] = *(const bf16x8*)(p + rd1);
    }
    if (t+1 < nt) stageA(d^1, 1, t+1);
    PHASE_SYNC; MFMA_PH(0,0); PHASE_END;
#pragma unroll
    for (int ni2=0; ni2<2; ++ni2) {
      const u16* p = Bs_d + (wc*64 + 32 + ni2*16)*64;
      Bf[2+ni2][0] = *(const bf16x8*)(p + rd0);
      Bf[2+ni2][1] = *(const bf16x8*)(p + rd1);
    }
    if (t+2 < nt) stageA(d, 0, t+2);
    PHASE_SYNC; MFMA_PH(0,1); PHASE_END;
#pragma unroll
    for (int mi2=0; mi2<4; ++mi2) {
      const u16* p = As_d + (wr*128 + 64 + mi2*16)*64;
      Af[mi2][0] = *(const bf16x8*)(p + rd0);
      Af[mi2][1] = *(const bf16x8*)(p + rd1);
    }
    if (t+2 < nt) stageB(d, 0, t+2);
    PHASE_SYNC; MFMA_PH(1,0); PHASE_END;
    if (t+2 < nt) stageB(d, 1, t+2);
    __builtin_amdgcn_s_barrier();
    __builtin_amdgcn_s_setprio(1);
    MFMA_PH(1,1);
    __builtin_amdgcn_s_setprio(0);
    if (t+2 < nt)      { asm volatile("s_waitcnt vmcnt(6)" ::: "memory"); }
    else if (t+1 < nt) { asm volatile("s_waitcnt vmcnt(0)" ::: "memory"); }
    __builtin_amdgcn_s_barrier();
  }

#pragma unroll
  for (int mi=0; mi<8; ++mi)
#pragma unroll
  for (int ni=0; ni<4; ++ni)
#pragma unroll
  for (int r=0; r<4; ++r) {
    int m = m0 + wr*128 + mi*16 + ((lane>>4)<<2) + r;
    int n = n0 + wc*64  + ni*16 + (lane & 15);
    float v = acc[mi][ni][r];
    if constexpr (EPI==2) {
      float u = 0.7978845608f*(v + 0.044715f*v*v*v);
      float th = 1.f - 2.f/(__expf(2.f*u)+1.f);
      v = 0.5f*v*(1.f + th);
    }
    if constexpr (EPI==3) v *= 0.0360843918f;   // 1/sqrt(768)
    if constexpr (MODE==3) {
      int seg = n / 3072, nn = n - seg*3072;
      u16* dst = seg==0 ? Cb : (seg==1 ? Cb2 : Cb3);
      dst[(long long)m*3072 + nn] = f2b(v);
    } else {
      long long ci;
      if constexpr (MODE==1) ci = (long long)z*SL*SL + (long long)m*SL + n;
      else                   ci = (long long)m*ldc + n;
      if constexpr (EPI==0) Cf[ci] = v; else Cb[ci] = f2b(v);
    }
  }
}

// ================= 256x128 8-phase BK=64 engine (MHA PV) =================
#define MFMA_Q(MB, NB, AF) \
  { _Pragma("unroll") for (int mi2=0; mi2<2; ++mi2) { \
      _Pragma("unroll") for (int ni2=0; ni2<2; ++ni2) { \
        acc[(MB)+mi2][(NB)+ni2] = __builtin_amdgcn_mfma_f32_16x16x32_bf16(AF[mi2][0], Bf[(NB)+ni2][0], acc[(MB)+mi2][(NB)+ni2], 0,0,0); \
        acc[(MB)+mi2][(NB)+ni2] = __builtin_amdgcn_mfma_f32_16x16x32_bf16(AF[mi2][1], Bf[(NB)+ni2][1], acc[(MB)+mi2][(NB)+ni2], 0,0,0); } } }

__global__ __launch_bounds__(512,2) void gemm128n_k(
    const u16* __restrict__ A, const u16* __restrict__ Bt, u16* __restrict__ Cb, int K)
{
  extern __shared__ u16 lds_dyn[];           // A [2][256][64] @0 | B [2][128][64] @32768
  const int tid = threadIdx.x, lane = tid & 63, wv = tid >> 6;
  const int wr = wv >> 1, wc = wv & 1;
  const int m0 = blockIdx.x * 256, n0 = blockIdx.y * 128, z = blockIdx.z;
  const int bb = z >> 2, hh = z & 3;
  const long long baseA = (long long)z*SL*SL;
  const long long baseB = ((long long)bb*3072 + hh*DKM)*SL;
  const int nt = K >> 6;

  const int rb = (wv*64 + lane) >> 3;
  const int sg = ((lane & 7) ^ (rb & 7)) * 8;
  const int rd0 = (lane & 15)*64 + (((lane>>4) ^ (lane & 7)) * 8);
  const int rd1 = rd0 ^ 32;

  auto stageA = [&](int buf, int half, int kt) {
#pragma unroll
    for (int tt = 0; tt < 2; ++tt) {
      const int t = half*2 + tt;             // contiguous: h0 rows [0,128) == phase mh0 reads
      gld16(lds_dyn + buf*16384 + t*4096 + wv*512,
            A + baseA + (long long)(m0 + t*64 + rb)*SL + (long long)kt*64 + sg);
    }
  };
  auto stageB = [&](int buf, int idx, int kt) {
    gld16(lds_dyn + 32768 + buf*8192 + idx*4096 + wv*512,
          Bt + baseB + (long long)(n0 + idx*64 + rb)*SL + (long long)kt*64 + sg);
  };

  f32x4 acc[4][4] = {};
  bf16x8 Af[2][2];
  bf16x8 Bf[4][2];

  stageA(0,0,0); stageB(0,0,0); stageB(0,1,0); stageA(0,1,0);
  stageA(1,0,1); stageB(1,0,1); stageB(1,1,1);
  asm volatile("s_waitcnt vmcnt(4)" ::: "memory");
  __builtin_amdgcn_s_barrier();

  for (int t = 0; t < nt; ++t) {
    const int d = t & 1;
    const u16* As_d = lds_dyn + d*16384;
    const u16* Bs_d = lds_dyn + 32768 + d*8192;
#pragma unroll
    for (int mi2=0; mi2<2; ++mi2) {
      const u16* p = As_d + (wr*32 + mi2*16)*64;
      Af[mi2][0] = *(const bf16x8*)(p + rd0);
      Af[mi2][1] = *(const bf16x8*)(p + rd1);
    }
#pragma unroll
    for (int ni2=0; ni2<2; ++ni2) {
      const u16* p = Bs_d + (wc*64 + ni2*16)*64;
      Bf[ni2][0] = *(const bf16x8*)(p + rd0);
      Bf[ni2][1] = *(const bf16x8*)(p + rd1);
    }
    if (t+1 < nt) stageA(d^1, 1, t+1);
    PHASE_SYNC; MFMA_Q(0,0,Af); PHASE_END;
#pragma unroll
    for (int ni2=0; ni2<2; ++ni2) {
      const u16* p = Bs_d + (wc*64 + 32 + ni2*16)*64;
      Bf[2+ni2][0] = *(const bf16x8*)(p + rd0);
      Bf[2+ni2][1] = *(const bf16x8*)(p + rd1);
    }
    if (t+2 < nt) stageA(d, 0, t+2);
    PHASE_SYNC; MFMA_Q(0,2,Af); PHASE_END;
#pragma unroll
    for (int mi2=0; mi2<2; ++mi2) {
      const u16* p = As_d + (128 + wr*32 + mi2*16)*64;
      Af[mi2][0] = *(const bf16x8*)(p + rd0);
      Af[mi2][1] = *(const bf16x8*)(p + rd1);
    }
    if (t+2 < nt) stageB(d, 0, t+2);
    PHASE_SYNC; MFMA_Q(2,0,Af); PHASE_END;
    if (t+2 < nt) stageB(d, 1, t+2);
    __builtin_amdgcn_s_barrier();
    __builtin_amdgcn_s_setprio(1);
    MFMA_Q(2,2,Af);
    __builtin_amdgcn_s_setprio(0);
    if (t+2 < nt)      { asm volatile("s_waitcnt vmcnt(4)" ::: "memory"); }
    else if (t+1 < nt) { asm volatile("s_waitcnt vmcnt(0)" ::: "memory"); }
    __builtin_amdgcn_s_barrier();
  }

  // epilogue: m rows striped: m = m0 + (mi>>1)*128 + wr*32 + (mi&1)*16 + (lane>>4)*4 + r
#pragma unroll
  for (int mi=0; mi<4; ++mi)
#pragma unroll
  for (int ni=0; ni<4; ++ni)
#pragma unroll
  for (int r=0; r<4; ++r) {
    int m = m0 + (mi>>1)*128 + wr*32 + (mi&1)*16 + ((lane>>4)<<2) + r;
    int n = n0 + wc*64 + ni*16 + (lane & 15);
    Cb[((long long)bb*SL + m)*3072 + hh*DKM + n] = f2b(acc[mi][ni][r]);
  }
}

// ---------------- legacy 128x128 BK=32 GEMM ----------------
// MODE 0: dense.  5: 3-way col scatter (768 segs).
template<int BM, int BN, int MODE, int EPI>
__global__ __launch_bounds__(256) void gemm_k(
    const u16* __restrict__ A, const u16* __restrict__ Bt,
    float* __restrict__ Cf, u16* __restrict__ Cb,
    u16* __restrict__ Cb2, u16* __restrict__ Cb3,
    int K, int lda, int ldb, int ldc)
{
  constexpr int BK = 32;
  constexpr int WM = BM/2, WN = BN/2, FM = WM/16, FN = WN/16;
  __shared__ __attribute__((aligned(16))) u16 As[BM*BK];
  __shared__ __attribute__((aligned(16))) u16 Bs[BN*BK];
  const int tid = threadIdx.x, lane = tid & 63, wv = tid >> 6;
  const int wr = wv >> 1, wc = wv & 1;
  const int m0 = blockIdx.x * BM, n0 = blockIdx.y * BN;

  f32x4 acc[FM][FN] = {};

  for (int kt = 0; kt < K; kt += BK) {
#pragma unroll
    for (int t = 0; t < (BM*4)/256; ++t) {
      int cb  = (t*4 + wv)*64;
      int ch  = cb + lane;
      int row = ch >> 2, cp = ch & 3;
      int gp  = cp ^ (row & 3) ^ ((row >> 2) & 1);
      long long ga = (long long)(m0 + row)*lda + (kt + gp*8);
      gld16(&As[cb*8], A + ga);
    }
#pragma unroll
    for (int t = 0; t < (BN*4)/256; ++t) {
      int cb  = (t*4 + wv)*64;
      int ch  = cb + lane;
      int row = ch >> 2, cp = ch & 3;
      int gp  = cp ^ (row & 3) ^ ((row >> 2) & 1);
      long long gb = (long long)(n0 + row)*ldb + (kt + gp*8);
      gld16(&Bs[cb*8], Bt + gb);
    }
    __syncthreads();
    bf16x8 af[FM], bfr[FN];
#pragma unroll
    for (int mi=0; mi<FM; ++mi) {
      int row = wr*WM + mi*16 + (lane & 15);
      int cp  = (lane >> 4) ^ (row & 3) ^ ((row >> 2) & 1);
      af[mi] = *reinterpret_cast<const bf16x8*>(&As[row*BK + cp*8]);
    }
#pragma unroll
    for (int ni=0; ni<FN; ++ni) {
      int row = wc*WN + ni*16 + (lane & 15);
      int cp  = (lane >> 4) ^ (row & 3) ^ ((row >> 2) & 1);
      bfr[ni] = *reinterpret_cast<const bf16x8*>(&Bs[row*BK + cp*8]);
    }
#pragma unroll
    for (int mi=0; mi<FM; ++mi)
#pragma unroll
      for (int ni=0; ni<FN; ++ni)
        acc[mi][ni] = __builtin_amdgcn_mfma_f32_16x16x32_bf16(af[mi], bfr[ni], acc[mi][ni], 0,0,0);
    __syncthreads();
  }

#pragma unroll
  for (int mi=0; mi<FM; ++mi)
#pragma unroll
  for (int ni=0; ni<FN; ++ni)
#pragma unroll
  for (int r=0; r<4; ++r) {
    int m = m0 + wr*WM + mi*16 + ((lane>>4)<<2) + r;
    int n = n0 + wc*WN + ni*16 + (lane & 15);
    float v = acc[mi][ni][r];
    if constexpr (MODE==5) {
      int seg = n / 768, nn = n - seg*768;
      u16* dst = seg==0 ? Cb : (seg==1 ? Cb2 : Cb3);
      dst[(long long)m*768 + nn] = f2b(v);
    } else {
      long long ci = (long long)m*ldc + n;
      if constexpr (EPI==0) Cf[ci] = v; else Cb[ci] = f2b(v);
    }
  }
}

// ================= fused sliding-window attention =================
__global__ __launch_bounds__(256) void sw_attn_k(
    const u16* __restrict__ Qm, const u16* __restrict__ Km,
    const u16* __restrict__ Vt, u16* __restrict__ Om)
{
  __shared__ __attribute__((aligned(16))) u16 Kb_s[64*64];
  __shared__ __attribute__((aligned(16))) u16 Vb_s[64*64];
  __shared__ __attribute__((aligned(16))) u16 Pb_s[4*32*64];
  const int tid = threadIdx.x, lane = tid & 63, wv = tid >> 6;
  const int qc = blockIdx.x >> 1, half = blockIdx.x & 1;
  const int h = blockIdx.y, b = blockIdx.z;
  const int q0 = qc*256 + half*128 + wv*32;
  const long long rowbase = (long long)b*SL;

  bf16x8 Qf[2][2];
#pragma unroll
  for (int mi=0;mi<2;++mi)
#pragma unroll
    for (int ks=0;ks<2;++ks)
      Qf[mi][ks] = *(const bf16x8*)(Qm + (rowbase + q0 + mi*16 + (lane&15))*DM + h*DH + ks*32 + (lane>>4)*8);

  f32x4 accO[2][4] = {};
  float mrun[2][4], lrun[2][4];
#pragma unroll
  for (int mi=0;mi<2;++mi)
#pragma unroll
    for (int r=0;r<4;++r){ mrun[mi][r]=-3e38f; lrun[mi][r]=0.f; }

  const int srow = tid >> 3;
  const int schunk = (tid & 7) ^ (srow & 7);

  const int kb0 = qc*256 + half*128 - 256;
  const int slo = kb0 < 0 ? ((-kb0) >> 6) : 0;
  const int shi_t = (SL - kb0) >> 6;
  const int shi = shi_t < 10 ? shi_t : 10;

  const int qpb = q0 + ((lane>>4)<<2);

  for (int s = slo; s < shi; ++s) {
    const int kb = kb0 + s*64;
#pragma unroll
    for (int ii=0; ii<2; ++ii) {
      gld16(Kb_s + ii*2048 + wv*512,
            Km + (rowbase + kb + srow + ii*32)*DM + h*DH + schunk*8);
      gld16(Vb_s + ii*2048 + wv*512,
            Vt + ((long long)b*DM + h*DH + srow + ii*32)*SL + kb + schunk*8);
    }
    asm volatile("s_waitcnt vmcnt(0)" ::: "memory");
    __syncthreads();

    f32x4 accS[2][4] = {};
    {
      bf16x8 Kf[4][2];
#pragma unroll
      for (int nf=0;nf<4;++nf){
        int row = nf*16 + (lane&15);
#pragma unroll
        for (int ks=0;ks<2;++ks){
          int ch = ((lane>>4) + ks*4) ^ (row&7);
          Kf[nf][ks] = *(const bf16x8*)(Kb_s + row*64 + ch*8);
        }
      }
#pragma unroll
      for (int mi=0;mi<2;++mi)
#pragma unroll
        for (int nf=0;nf<4;++nf){
          accS[mi][nf] = __builtin_amdgcn_mfma_f32_16x16x32_bf16(Qf[mi][0], Kf[nf][0], accS[mi][nf], 0,0,0);
          accS[mi][nf] = __builtin_amdgcn_mfma_f32_16x16x32_bf16(Qf[mi][1], Kf[nf][1], accS[mi][nf], 0,0,0);
        }
    }

    float smax[2][4];
#pragma unroll
    for (int mi=0;mi<2;++mi)
#pragma unroll
      for (int r=0;r<4;++r) smax[mi][r] = -3e38f;
#pragma unroll
    for (int mi=0;mi<2;++mi)
#pragma unroll
      for (int nf=0;nf<4;++nf)
#pragma unroll
        for (int r=0;r<4;++r){
          int dd = (kb + nf*16 + (lane&15)) - (qpb + mi*16 + r);
          bool ok = (dd <= 256) && (dd >= -256);
          float v = ok ? accS[mi][nf][r]*0.125f : -3e38f;
          accS[mi][nf][r] = v;
          smax[mi][r] = fmaxf(smax[mi][r], v);
        }
#pragma unroll
    for (int mi=0;mi<2;++mi)
#pragma unroll
      for (int r=0;r<4;++r){
        float v = smax[mi][r];
        v = fmaxf(v, __shfl_xor(v,1,64)); v = fmaxf(v, __shfl_xor(v,2,64));
        v = fmaxf(v, __shfl_xor(v,4,64)); v = fmaxf(v, __shfl_xor(v,8,64));
        smax[mi][r] = v;
      }

#pragma unroll
    for (int mi=0;mi<2;++mi)
#pragma unroll
      for (int r=0;r<4;++r){
        float mn = fmaxf(mrun[mi][r], smax[mi][r]);
        float sc = __expf(mrun[mi][r] - mn);
        float ls = 0.f;
#pragma unroll
        for (int nf=0;nf<4;++nf){
          float sv = accS[mi][nf][r];
          float p = (sv > -1e37f) ? __expf(sv - mn) : 0.f;
          accS[mi][nf][r] = p;
          ls += p;
        }
        ls += __shfl_xor(ls,1,64); ls += __shfl_xor(ls,2,64);
        ls += __shfl_xor(ls,4,64); ls += __shfl_xor(ls,8,64);
        lrun[mi][r] = lrun[mi][r]*sc + ls;
        mrun[mi][r] = mn;
#pragma unroll
        for (int df=0;df<4;++df) accO[mi][df][r] *= sc;
      }
#pragma unroll
    for (int mi=0;mi<2;++mi)
#pragma unroll
      for (int nf=0;nf<4;++nf)
#pragma unroll
        for (int r=0;r<4;++r){
          int ql = mi*16 + ((lane>>4)<<2) + r;
          int k  = nf*16 + (lane&15);
          int ch = (k>>3) ^ (ql&7);
          Pb_s[wv*2048 + ql*64 + ch*8 + (k&7)] = f2b(accS[mi][nf][r]);
        }
    asm volatile("s_waitcnt lgkmcnt(0)" ::: "memory");
    __builtin_amdgcn_sched_barrier(0);

    {
      bf16x8 Pf[2][2], Vf[4][2];
#pragma unroll
      for (int mi=0;mi<2;++mi){
        int ql = mi*16 + (lane&15);
#pragma unroll
        for (int ks=0;ks<2;++ks){
          int ch = ((lane>>4) + ks*4) ^ (ql&7);
          Pf[mi][ks] = *(const bf16x8*)(Pb_s + wv*2048 + ql*64 + ch*8);
        }
      }
#pragma unroll
      for (int df=0;df<4;++df){
        int dr = df*16 + (lane&15);
#pragma unroll
        for (int ks=0;ks<2;++ks){
          int ch = ((lane>>4) + ks*4) ^ (dr&7);
          Vf[df][ks] = *(const bf16x8*)(Vb_s + dr*64 + ch*8);
        }
      }
#pragma unroll
      for (int mi=0;mi<2;++mi)
#pragma unroll
        for (int df=0;df<4;++df){
          accO[mi][df] = __builtin_amdgcn_mfma_f32_16x16x32_bf16(Pf[mi][0], Vf[df][0], accO[mi][df], 0,0,0);
          accO[mi][df] = __builtin_amdgcn_mfma_f32_16x16x32_bf16(Pf[mi][1], Vf[df][1], accO[mi][df], 0,0,0);
        }
    }
    __syncthreads();
  }

#pragma unroll
  for (int mi=0;mi<2;++mi)
#pragma unroll
    for (int df=0;df<4;++df)
#pragma unroll
      for (int r=0;r<4;++r){
        long long row = rowbase + qpb + mi*16 + r;
        int col = h*DH + df*16 + (lane&15);
        Om[row*DM + col] = f2b(accO[mi][df][r] / lrun[mi][r]);
      }
}

// ---------------- pointwise / small kernels ----------------
__global__ __launch_bounds__(256) void embed_ln_k(const int* __restrict__ x,
    const float* __restrict__ emb, const float* __restrict__ pos,
    const float* __restrict__ g, const float* __restrict__ bta,
    float* __restrict__ of, u16* __restrict__ ob)
{
  __shared__ float sm[4];
  const int row = blockIdx.x, s = row & (SL-1);
  const long long tok = x[row];
  const float* e = emb + tok*DM;
  const float* p = pos + (long long)s*DM;
  float v[3], su=0.f, sq=0.f;
#pragma unroll
  for (int i=0;i<3;++i){ int d=threadIdx.x+i*256; v[i]=e[d]+p[d]; su+=v[i]; sq+=v[i]*v[i]; }
  su = bred_sum(su, sm); sq = bred_sum(sq, sm);
  float mean = su*(1.f/DM), var = sq*(1.f/DM)-mean*mean, rs = rsqrtf(var+1e-5f);
#pragma unroll
  for (int i=0;i<3;++i){ int d=threadIdx.x+i*256;
    float o = (v[i]-mean)*rs*g[d] + bta[d];
    of[(long long)row*DM+d]=o; ob[(long long)row*DM+d]=f2b(o); }
}

// a + c -> LN
__global__ __launch_bounds__(256) void resid_ln_k(const float* __restrict__ a, const float* __restrict__ c,
    const float* __restrict__ g, const float* __restrict__ bta,
    float* __restrict__ of, u16* __restrict__ ob)
{
  __shared__ float sm[4];
  const long long row = blockIdx.x;
  const float* ra = a + row*DM;
  const float* rc = c + row*DM;
  float v[3], su=0.f, sq=0.f;
#pragma unroll
  for (int i=0;i<3;++i){
    int d=threadIdx.x+i*256;
    v[i]=ra[d]+rc[d];
    su+=v[i]; sq+=v[i]*v[i];
  }
  su = bred_sum(su, sm); sq = bred_sum(sq, sm);
  float mean = su*(1.f/DM), var = sq*(1.f/DM)-mean*mean, rs = rsqrtf(var+1e-5f);
#pragma unroll
  for (int i=0;i<3;++i){ int d=threadIdx.x+i*256;
    float o = (v[i]-mean)*rs*g[d] + bta[d];
    of[row*DM+d]=o; if (ob) ob[row*DM+d]=f2b(o); }
}

// fp32 [Kd,Nd] -> bf16 [Nd,Kd]
__global__ __launch_bounds__(256) void transp_w_k(const float* __restrict__ W, u16* __restrict__ Wt, int Kd, int Nd)
{
  __shared__ float t[32][33];
  int n0 = blockIdx.x*32, k0 = blockIdx.y*32;
  int lx = threadIdx.x & 31, ly = threadIdx.x >> 5;
#pragma unroll
  for (int i=0;i<4;++i) t[ly+i*8][lx] = W[(long long)(k0+ly+i*8)*Nd + n0+lx];
  __syncthreads();
#pragma unroll
  for (int i=0;i<4;++i) Wt[(long long)(n0+ly+i*8)*Kd + k0+lx] = f2b(t[lx][ly+i*8]);
}

// bf16 [8192,Nc] -> bf16 [B][Nc][SL]
__global__ __launch_bounds__(256) void transp_b_k(const u16* __restrict__ in, u16* __restrict__ out, int Nc)
{
  __shared__ u16 t[32][33];
  int c0 = blockIdx.x*32, r0 = blockIdx.y*32;
  int lx = threadIdx.x & 31, ly = threadIdx.x >> 5;
#pragma unroll
  for (int i=0;i<4;++i) t[ly+i*8][lx] = in[(long long)(r0+ly+i*8)*Nc + c0+lx];
  __syncthreads();
  int b = r0 >> 11, s0 = r0 & (SL-1);
#pragma unroll
  for (int i=0;i<4;++i) out[((long long)b*Nc + c0+ly+i*8)*SL + s0+lx] = t[lx][ly+i*8];
}

// outer-MHA softmax: one wave per row, in-place on pre-scaled bf16 scores
__global__ __launch_bounds__(256) void mha_softmax_k(u16* __restrict__ sc, const int* __restrict__ x)
{
  const int r = blockIdx.x*4 + (threadIdx.x >> 6);
  const int lane = threadIdx.x & 63;
  const int z = r >> 11;
  const int b = z >> 2;
  u16* row = sc + (long long)z*SL*SL + (long long)(r & (SL-1))*SL;
  const int* xb = x + b*SL;
  float v[32]; float mx = -3e38f;
#pragma unroll
  for (int i=0;i<4;++i){
    const int j0 = i*512 + lane*8;
    u16x8 pv = *(const u16x8*)(row + j0);
    i32x4 xa = *(const i32x4*)(xb + j0);
    i32x4 xc = *(const i32x4*)(xb + j0 + 4);
#pragma unroll
    for (int e=0;e<8;++e){
      int xv = e<4 ? xa[e] : xc[e-4];
      float f = (xv != 0) ? b2f(pv[e]) : -3e38f;
      v[i*8+e] = f;
      mx = fmaxf(mx, f);
    }
  }
  mx = wred_max(mx);
  float s = 0.f;
#pragma unroll
  for (int i=0;i<32;++i){ v[i] = (v[i] > -1e37f) ? __expf(v[i]-mx) : 0.f; s += v[i]; }
  s = wred_sum(s);
  float inv = 1.f/s;
#pragma unroll
  for (int i=0;i<4;++i){
    u16x8 ov;
#pragma unroll
    for (int e=0;e<8;++e) ov[e] = f2b(v[i*8+e]*inv);
    *(u16x8*)(row + i*512 + lane*8) = ov;
  }
}

__global__ __launch_bounds__(256) void pool_part_k(const float* __restrict__ f, float* __restrict__ pp)
{
  int b = blockIdx.x, ch = blockIdx.y;
  float m0=-3e38f, m1=-3e38f, m2=-3e38f;
  for (int s = ch*32; s < ch*32+32; ++s){
    const float* r = f + ((long long)b*SL + s)*DM;
    m0=fmaxf(m0,r[threadIdx.x]); m1=fmaxf(m1,r[threadIdx.x+256]); m2=fmaxf(m2,r[threadIdx.x+512]);
  }
  float* o = pp + (long long)(b*64+ch)*DM;
  o[threadIdx.x]=m0; o[threadIdx.x+256]=m1; o[threadIdx.x+512]=m2;
}

__global__ __launch_bounds__(256) void pool_red_k(const float* __restrict__ pp, float* __restrict__ out)
{
  int b = blockIdx.x;
#pragma unroll
  for (int i=0;i<3;++i){
    int d = threadIdx.x + i*256;
    float m = -3e38f;
    for (int c=0;c<64;++c) m = fmaxf(m, pp[(long long)(b*64+c)*DM + d]);
    out[(long long)b*DM + d] = m;
  }
}

// ---------------- orchestration ----------------
extern "C" void kernel_launch(void* const* d_in, const int* in_sizes, int n_in,
                              void* d_out, int out_size, void* d_ws, size_t ws_size,
                              hipStream_t stream)
{
  const int*   x      = (const int*)  d_in[0];
  const float* emb    = (const float*)d_in[1];
  const float* pos    = (const float*)d_in[2];
  const float* ln_e_g = (const float*)d_in[3];
  const float* ln_e_b = (const float*)d_in[4];
  const float* lf_wq  = (const float*)d_in[5];
  const float* lf_wk  = (const float*)d_in[6];
  const float* lf_wv  = (const float*)d_in[7];
  const float* lf_wo  = (const float*)d_in[8];
  const float* ln1_g  = (const float*)d_in[9];
  const float* ln1_b  = (const float*)d_in[10];
  const float* w1     = (const float*)d_in[11];
  const float* w2     = (const float*)d_in[12];
  const float* ln2_g  = (const float*)d_in[13];
  const float* ln2_b  = (const float*)d_in[14];
  const float* mha_wq = (const float*)d_in[15];
  const float* mha_wk = (const float*)d_in[16];
  const float* mha_wv = (const float*)d_in[17];
  const float* mha_fc = (const float*)d_in[18];
  const float* mha_ln_g = (const float*)d_in[19];
  const float* mha_ln_b = (const float*)d_in[20];

  (void)hipFuncSetAttribute((const void*)gemm256_k<0,2>, hipFuncAttributeMaxDynamicSharedMemorySize, 131072);
  (void)hipFuncSetAttribute((const void*)gemm256_k<1,3>, hipFuncAttributeMaxDynamicSharedMemorySize, 131072);
  (void)hipFuncSetAttribute((const void*)gemm256_k<3,1>, hipFuncAttributeMaxDynamicSharedMemorySize, 131072);
  (void)hipFuncSetAttribute((const void*)gemm128n_k,     hipFuncAttributeMaxDynamicSharedMemorySize, 98304);

  const long long R = 8192;           // B*S rows
  float* F0 = (float*)d_ws;           // h / out_lf (fp32)
  float* F1 = F0 + R*DM;              // gemm fp32 out
  float* F2 = F1 + R*DM;              // h2 / final ln
  u16* B0 = (u16*)(F2 + R*DM);        // h bf16 -> attn-out bf16
  u16* B1 = B0 + R*DM;                // lf q -> h2 bf16
  u16* B2 = B1 + R*DM;                // lf k -> out_lf bf16
  u16* B3 = B2 + R*DM;                // lf v^T [B][768][SL]
  u16* WT = B3 + R*DM;                // transposed weights (bf16, up to 9216x768)
  u16* G1 = WT + (long long)9216*DM;  // gelu-out / mha q
  u16* G2 = G1 + R*DFF;               // mha k -> mha o
  u16* G3 = G2 + R*DFF;               // mha v^T [B][3072][SL]
  u16* SC = G3 + R*DFF;               // lf/mha v temp, mha P (134MB)
  float* PP = (float*)(SC + (long long)16*SL*SL);   // pool partials (4x64x768)

  dim3 T(256), T5(512);
  const size_t SM256 = 131072, SM128 = 98304;

  // ---- longformer layer
  embed_ln_k<<<dim3(8192), T, 0, stream>>>(x, emb, pos, ln_e_g, ln_e_b, F0, B0);

  // fused lf qkv: WT = [q|k|v]^T (2304x768), scatter -> B1,B2,SC
  transp_w_k<<<dim3(24,24), T, 0, stream>>>(lf_wq, WT,               DM, DM);
  transp_w_k<<<dim3(24,24), T, 0, stream>>>(lf_wk, WT + 768*768,     DM, DM);
  transp_w_k<<<dim3(24,24), T, 0, stream>>>(lf_wv, WT + 2*768*768,   DM, DM);
  gemm_k<128,128,5,1><<<dim3(64,18), T, 0, stream>>>(B0, WT, nullptr, B1, B2, SC, DM, DM, DM, 0);
  transp_b_k<<<dim3(24,256), T, 0, stream>>>(SC, B3, DM);

  sw_attn_k<<<dim3(16,12,4), T, 0, stream>>>(B1, B2, B3, B0);

  transp_w_k<<<dim3(24,24), T, 0, stream>>>(lf_wo, WT, DM, DM);
  gemm_k<128,128,0,0><<<dim3(64,6), T, 0, stream>>>(B0, WT, F1, nullptr, nullptr, nullptr, DM, DM, DM, DM);
  resid_ln_k<<<dim3(8192), T, 0, stream>>>(F0, F1, ln1_g, ln1_b, F2, B1);

  transp_w_k<<<dim3(96,24), T, 0, stream>>>(w1, WT, DM, DFF);
  gemm256_k<0,2><<<dim3(32,12,1), T5, SM256, stream>>>(B1, WT, nullptr, G1, nullptr, nullptr, DM, DM, DM, DFF);
  transp_w_k<<<dim3(24,96), T, 0, stream>>>(w2, WT, DFF, DM);
  gemm_k<128,128,0,0><<<dim3(64,6), T, 0, stream>>>(G1, WT, F1, nullptr, nullptr, nullptr, DFF, DFF, DFF, DM);
  resid_ln_k<<<dim3(8192), T, 0, stream>>>(F2, F1, ln2_g, ln2_b, F0, B2);

  // ---- outer MHA: fused qkv (WT = [wq|wk|wv]^T 9216x768), scatter -> G1,G2,SC
  transp_w_k<<<dim3(96,24), T, 0, stream>>>(mha_wq, WT,                 DM, DFF);
  transp_w_k<<<dim3(96,24), T, 0, stream>>>(mha_wk, WT + (long long)3072*768, DM, DFF);
  transp_w_k<<<dim3(96,24), T, 0, stream>>>(mha_wv, WT + (long long)6144*768, DM, DFF);
  gemm256_k<3,1><<<dim3(32,36,1), T5, SM256, stream>>>(B2, WT, nullptr, G1, G2, SC, DM, DM, DM, 0);
  transp_b_k<<<dim3(96,256), T, 0, stream>>>(SC, G3, DFF);

  gemm256_k<1,3><<<dim3(8,8,16), T5, SM256, stream>>>(G1, G2, nullptr, SC, nullptr, nullptr, DKM, 3072, 3072, 0);
  mha_softmax_k<<<dim3(8192), T, 0, stream>>>(SC, x);
  gemm128n_k<<<dim3(8,6,16), T5, SM128, stream>>>(SC, G3, G2, SL);

  transp_w_k<<<dim3(24,96), T, 0, stream>>>(mha_fc, WT, DFF, DM);
  gemm_k<128,128,0,0><<<dim3(64,6), T, 0, stream>>>(G2, WT, F1, nullptr, nullptr, nullptr, DFF, DFF, DFF, DM);
  resid_ln_k<<<dim3(8192), T, 0, stream>>>(F0, F1, mha_ln_g, mha_ln_b, F2, nullptr);

  pool_part_k<<<dim3(4,64), T, 0, stream>>>(F2, PP);
  pool_red_k<<<dim3(4), T, 0, stream>>>(PP, (float*)d_out);
}

// Round 12
// 927.986 us; speedup vs baseline: 1.0467x; 1.0142x over previous
//
#include <hip/hip_runtime.h>
#include <hip/hip_bf16.h>
#include <math.h>

#define DEV static __device__ __forceinline__

typedef unsigned short u16;
typedef __attribute__((ext_vector_type(8))) __bf16 bf16x8;
typedef __attribute__((ext_vector_type(8))) unsigned short u16x8;
typedef __attribute__((ext_vector_type(4))) float f32x4;
typedef __attribute__((ext_vector_type(4))) int i32x4;

constexpr int SL  = 2048;   // seq len
constexpr int DM  = 768;    // d_model
constexpr int DH  = 64;     // longformer head dim
constexpr int DFF = 3072;
constexpr int DKM = 768;    // outer-MHA head dim

DEV float b2f(u16 u){ union{float f; unsigned u;} c; c.u = ((unsigned)u)<<16; return c.f; }
DEV u16 f2b(float f){ union{float f; unsigned u;} c; c.f=f; unsigned r=(c.u + 0x7fffu + ((c.u>>16)&1u))>>16; return (u16)r; }

DEV void gld16(u16* lds, const u16* g){
  __builtin_amdgcn_global_load_lds((const __attribute__((address_space(1))) void*)g,
                                   (__attribute__((address_space(3))) void*)lds, 16, 0, 0);
}

// ---------------- reductions ----------------
DEV float wred_sum(float v){
#pragma unroll
  for (int o=32;o;o>>=1) v += __shfl_xor(v,o,64);
  return v;
}
DEV float wred_max(float v){
#pragma unroll
  for (int o=32;o;o>>=1) v = fmaxf(v, __shfl_xor(v,o,64));
  return v;
}
DEV float bred_sum(float v, float* sm){
  v = wred_sum(v);
  if ((threadIdx.x & 63)==0) sm[threadIdx.x>>6] = v;
  __syncthreads();
  float r = sm[0]+sm[1]+sm[2]+sm[3];
  __syncthreads();
  return r;
}

#define PHASE_SYNC \
  __builtin_amdgcn_s_barrier(); \
  asm volatile("s_waitcnt lgkmcnt(0)" ::: "memory"); \
  __builtin_amdgcn_sched_barrier(0); \
  __builtin_amdgcn_s_setprio(1);
#define PHASE_END \
  __builtin_amdgcn_s_setprio(0); \
  __builtin_amdgcn_s_barrier();

// ================= 256x256 8-phase BK=64 MFMA GEMM =================
// C = A[M,K] * Bt[N,K]^T, fp32 accum, bf16 inputs.
// MODE 0: dense.  1: MHA scores (z=(b,h)).  3: 3-way col scatter (3072 segs).
// EPI 0: fp32. 1: bf16. 2: fast-gelu+bf16. 3: *1/sqrt(768)+bf16.
#define MFMA_PH(MH, NH) \
  { _Pragma("unroll") for (int mi2=0; mi2<4; ++mi2) { \
      _Pragma("unroll") for (int ni2=0; ni2<2; ++ni2) { \
        acc[(MH)*4+mi2][(NH)*2+ni2] = __builtin_amdgcn_mfma_f32_16x16x32_bf16(Af[mi2][0], Bf[(NH)*2+ni2][0], acc[(MH)*4+mi2][(NH)*2+ni2], 0,0,0); \
        acc[(MH)*4+mi2][(NH)*2+ni2] = __builtin_amdgcn_mfma_f32_16x16x32_bf16(Af[mi2][1], Bf[(NH)*2+ni2][1], acc[(MH)*4+mi2][(NH)*2+ni2], 0,0,0); } } }

template<int MODE, int EPI>
__global__ __launch_bounds__(512,2) void gemm256_k(
    const u16* __restrict__ A, const u16* __restrict__ Bt,
    float* __restrict__ Cf, u16* __restrict__ Cb,
    u16* __restrict__ Cb2, u16* __restrict__ Cb3,
    int K, int lda, int ldb, int ldc)
{
  extern __shared__ u16 lds_dyn[];           // [2][256][64] A | [2][256][64] B
  const int tid = threadIdx.x, lane = tid & 63, wv = tid >> 6;
  const int wr = wv >> 2, wc = wv & 3;
  const int m0 = blockIdx.x * 256, n0 = blockIdx.y * 256, z = blockIdx.z;
  const int nt = K >> 6;

  int bb = 0, hh = 0;
  long long baseA = 0, baseB = 0;
  if constexpr (MODE==1) { bb=z>>2; hh=z&3; baseA=(long long)bb*SL*3072 + hh*DKM; baseB=baseA; }

  const int rb = (wv*64 + lane) >> 3;
  const int sg = ((lane & 7) ^ (rb & 7)) * 8;
  const int rd0 = (lane & 15)*64 + (((lane>>4) ^ (lane & 7)) * 8);
  const int rd1 = rd0 ^ 32;

  auto stageA = [&](int buf, int half, int kt) {
#pragma unroll
    for (int tt = 0; tt < 2; ++tt) {
      const int t = half + tt*2;             // INTERLEAVED halves: h0={0,2}, h1={1,3}
      gld16(lds_dyn + buf*16384 + t*4096 + wv*512,
            A + baseA + (long long)(m0 + t*64 + rb)*lda + (long long)kt*64 + sg);
    }
  };
  auto stageB = [&](int buf, int half, int kt) {
#pragma unroll
    for (int tt = 0; tt < 2; ++tt) {
      const int t = half*2 + tt;             // contiguous (all B reads finish by end of Q1)
      gld16(lds_dyn + 32768 + buf*16384 + t*4096 + wv*512,
            Bt + baseB + (long long)(n0 + t*64 + rb)*ldb + (long long)kt*64 + sg);
    }
  };

  f32x4 acc[8][4] = {};
  bf16x8 Af[4][2];
  bf16x8 Bf[4][2];

  stageA(0,0,0); stageB(0,0,0); stageB(0,1,0); stageA(0,1,0);
  stageA(1,0,1); stageB(1,0,1); stageB(1,1,1);
  asm volatile("s_waitcnt vmcnt(6)" ::: "memory");
  __builtin_amdgcn_s_barrier();

  for (int t = 0; t < nt; ++t) {
    const int d = t & 1;
    const u16* As_d = lds_dyn + d*16384;
    const u16* Bs_d = lds_dyn + 32768 + d*16384;
#pragma unroll
    for (int mi2=0; mi2<4; ++mi2) {
      const u16* p = As_d + (wr*128 + mi2*16)*64;
      Af[mi2][0] = *(const bf16x8*)(p + rd0);
      Af[mi2][1] = *(const bf16x8*)(p + rd1);
    }
#pragma unroll
    for (int ni2=0; ni2<2; ++ni2) {
      const u16* p = Bs_d + (wc*64 + ni2*16)*64;
      Bf[ni2][0] = *(const bf16x8*)(p + rd0);
      Bf[ni2][1] = *(const bf16x8*)(p + rd1);
    }
    if (t+1 < nt) stageA(d^1, 1, t+1);
    PHASE_SYNC; MFMA_PH(0,0); PHASE_END;
#pragma unroll
    for (int ni2=0; ni2<2; ++ni2) {
      const u16* p = Bs_d + (wc*64 + 32 + ni2*16)*64;
      Bf[2+ni2][0] = *(const bf16x8*)(p + rd0);
      Bf[2+ni2][1] = *(const bf16x8*)(p + rd1);
    }
    if (t+2 < nt) stageA(d, 0, t+2);
    PHASE_SYNC; MFMA_PH(0,1); PHASE_END;
#pragma unroll
    for (int mi2=0; mi2<4; ++mi2) {
      const u16* p = As_d + (wr*128 + 64 + mi2*16)*64;
      Af[mi2][0] = *(const bf16x8*)(p + rd0);
      Af[mi2][1] = *(const bf16x8*)(p + rd1);
    }
    if (t+2 < nt) stageB(d, 0, t+2);
    PHASE_SYNC; MFMA_PH(1,0); PHASE_END;
    if (t+2 < nt) stageB(d, 1, t+2);
    __builtin_amdgcn_s_barrier();
    __builtin_amdgcn_s_setprio(1);
    MFMA_PH(1,1);
    __builtin_amdgcn_s_setprio(0);
    if (t+2 < nt)      { asm volatile("s_waitcnt vmcnt(6)" ::: "memory"); }
    else if (t+1 < nt) { asm volatile("s_waitcnt vmcnt(0)" ::: "memory"); }
    __builtin_amdgcn_s_barrier();
  }

#pragma unroll
  for (int mi=0; mi<8; ++mi)
#pragma unroll
  for (int ni=0; ni<4; ++ni)
#pragma unroll
  for (int r=0; r<4; ++r) {
    int m = m0 + wr*128 + mi*16 + ((lane>>4)<<2) + r;
    int n = n0 + wc*64  + ni*16 + (lane & 15);
    float v = acc[mi][ni][r];
    if constexpr (EPI==2) {
      float u = 0.7978845608f*(v + 0.044715f*v*v*v);
      float th = 1.f - 2.f/(__expf(2.f*u)+1.f);
      v = 0.5f*v*(1.f + th);
    }
    if constexpr (EPI==3) v *= 0.0360843918f;   // 1/sqrt(768)
    if constexpr (MODE==3) {
      int seg = n / 3072, nn = n - seg*3072;
      u16* dst = seg==0 ? Cb : (seg==1 ? Cb2 : Cb3);
      dst[(long long)m*3072 + nn] = f2b(v);
    } else {
      long long ci;
      if constexpr (MODE==1) ci = (long long)z*SL*SL + (long long)m*SL + n;
      else                   ci = (long long)m*ldc + n;
      if constexpr (EPI==0) Cf[ci] = v; else Cb[ci] = f2b(v);
    }
  }
}

// ================= 256x128 8-phase BK=64 engine (MHA PV) =================
#define MFMA_Q(MB, NB, AF) \
  { _Pragma("unroll") for (int mi2=0; mi2<2; ++mi2) { \
      _Pragma("unroll") for (int ni2=0; ni2<2; ++ni2) { \
        acc[(MB)+mi2][(NB)+ni2] = __builtin_amdgcn_mfma_f32_16x16x32_bf16(AF[mi2][0], Bf[(NB)+ni2][0], acc[(MB)+mi2][(NB)+ni2], 0,0,0); \
        acc[(MB)+mi2][(NB)+ni2] = __builtin_amdgcn_mfma_f32_16x16x32_bf16(AF[mi2][1], Bf[(NB)+ni2][1], acc[(MB)+mi2][(NB)+ni2], 0,0,0); } } }

__global__ __launch_bounds__(512,2) void gemm128n_k(
    const u16* __restrict__ A, const u16* __restrict__ Bt, u16* __restrict__ Cb, int K)
{
  extern __shared__ u16 lds_dyn[];           // A [2][256][64] @0 | B [2][128][64] @32768
  const int tid = threadIdx.x, lane = tid & 63, wv = tid >> 6;
  const int wr = wv >> 1, wc = wv & 1;
  const int m0 = blockIdx.x * 256, n0 = blockIdx.y * 128, z = blockIdx.z;
  const int bb = z >> 2, hh = z & 3;
  const long long baseA = (long long)z*SL*SL;
  const long long baseB = ((long long)bb*3072 + hh*DKM)*SL;
  const int nt = K >> 6;

  const int rb = (wv*64 + lane) >> 3;
  const int sg = ((lane & 7) ^ (rb & 7)) * 8;
  const int rd0 = (lane & 15)*64 + (((lane>>4) ^ (lane & 7)) * 8);
  const int rd1 = rd0 ^ 32;

  auto stageA = [&](int buf, int half, int kt) {
#pragma unroll
    for (int tt = 0; tt < 2; ++tt) {
      const int t = half*2 + tt;             // contiguous: h0 rows [0,128) == phase mh0 reads
      gld16(lds_dyn + buf*16384 + t*4096 + wv*512,
            A + baseA + (long long)(m0 + t*64 + rb)*SL + (long long)kt*64 + sg);
    }
  };
  auto stageB = [&](int buf, int idx, int kt) {
    gld16(lds_dyn + 32768 + buf*8192 + idx*4096 + wv*512,
          Bt + baseB + (long long)(n0 + idx*64 + rb)*SL + (long long)kt*64 + sg);
  };

  f32x4 acc[4][4] = {};
  bf16x8 Af[2][2];
  bf16x8 Bf[4][2];

  stageA(0,0,0); stageB(0,0,0); stageB(0,1,0); stageA(0,1,0);
  stageA(1,0,1); stageB(1,0,1); stageB(1,1,1);
  asm volatile("s_waitcnt vmcnt(4)" ::: "memory");
  __builtin_amdgcn_s_barrier();

  for (int t = 0; t < nt; ++t) {
    const int d = t & 1;
    const u16* As_d = lds_dyn + d*16384;
    const u16* Bs_d = lds_dyn + 32768 + d*8192;
#pragma unroll
    for (int mi2=0; mi2<2; ++mi2) {
      const u16* p = As_d + (wr*32 + mi2*16)*64;
      Af[mi2][0] = *(const bf16x8*)(p + rd0);
      Af[mi2][1] = *(const bf16x8*)(p + rd1);
    }
#pragma unroll
    for (int ni2=0; ni2<2; ++ni2) {
      const u16* p = Bs_d + (wc*64 + ni2*16)*64;
      Bf[ni2][0] = *(const bf16x8*)(p + rd0);
      Bf[ni2][1] = *(const bf16x8*)(p + rd1);
    }
    if (t+1 < nt) stageA(d^1, 1, t+1);
    PHASE_SYNC; MFMA_Q(0,0,Af); PHASE_END;
#pragma unroll
    for (int ni2=0; ni2<2; ++ni2) {
      const u16* p = Bs_d + (wc*64 + 32 + ni2*16)*64;
      Bf[2+ni2][0] = *(const bf16x8*)(p + rd0);
      Bf[2+ni2][1] = *(const bf16x8*)(p + rd1);
    }
    if (t+2 < nt) stageA(d, 0, t+2);
    PHASE_SYNC; MFMA_Q(0,2,Af); PHASE_END;
#pragma unroll
    for (int mi2=0; mi2<2; ++mi2) {
      const u16* p = As_d + (128 + wr*32 + mi2*16)*64;
      Af[mi2][0] = *(const bf16x8*)(p + rd0);
      Af[mi2][1] = *(const bf16x8*)(p + rd1);
    }
    if (t+2 < nt) stageB(d, 0, t+2);
    PHASE_SYNC; MFMA_Q(2,0,Af); PHASE_END;
    if (t+2 < nt) stageB(d, 1, t+2);
    __builtin_amdgcn_s_barrier();
    __builtin_amdgcn_s_setprio(1);
    MFMA_Q(2,2,Af);
    __builtin_amdgcn_s_setprio(0);
    if (t+2 < nt)      { asm volatile("s_waitcnt vmcnt(4)" ::: "memory"); }
    else if (t+1 < nt) { asm volatile("s_waitcnt vmcnt(0)" ::: "memory"); }
    __builtin_amdgcn_s_barrier();
  }

  // epilogue: m rows striped: m = m0 + (mi>>1)*128 + wr*32 + (mi&1)*16 + (lane>>4)*4 + r
#pragma unroll
  for (int mi=0; mi<4; ++mi)
#pragma unroll
  for (int ni=0; ni<4; ++ni)
#pragma unroll
  for (int r=0; r<4; ++r) {
    int m = m0 + (mi>>1)*128 + wr*32 + (mi&1)*16 + ((lane>>4)<<2) + r;
    int n = n0 + wc*64 + ni*16 + (lane & 15);
    Cb[((long long)bb*SL + m)*3072 + hh*DKM + n] = f2b(acc[mi][ni][r]);
  }
}

// ---------------- legacy 128x128 BK=32 GEMM ----------------
// MODE 0: dense.  5: 3-way col scatter (768 segs).
template<int BM, int BN, int MODE, int EPI>
__global__ __launch_bounds__(256) void gemm_k(
    const u16* __restrict__ A, const u16* __restrict__ Bt,
    float* __restrict__ Cf, u16* __restrict__ Cb,
    u16* __restrict__ Cb2, u16* __restrict__ Cb3,
    int K, int lda, int ldb, int ldc)
{
  constexpr int BK = 32;
  constexpr int WM = BM/2, WN = BN/2, FM = WM/16, FN = WN/16;
  __shared__ __attribute__((aligned(16))) u16 As[BM*BK];
  __shared__ __attribute__((aligned(16))) u16 Bs[BN*BK];
  const int tid = threadIdx.x, lane = tid & 63, wv = tid >> 6;
  const int wr = wv >> 1, wc = wv & 1;
  const int m0 = blockIdx.x * BM, n0 = blockIdx.y * BN;

  f32x4 acc[FM][FN] = {};

  for (int kt = 0; kt < K; kt += BK) {
#pragma unroll
    for (int t = 0; t < (BM*4)/256; ++t) {
      int cb  = (t*4 + wv)*64;
      int ch  = cb + lane;
      int row = ch >> 2, cp = ch & 3;
      int gp  = cp ^ (row & 3) ^ ((row >> 2) & 1);
      long long ga = (long long)(m0 + row)*lda + (kt + gp*8);
      gld16(&As[cb*8], A + ga);
    }
#pragma unroll
    for (int t = 0; t < (BN*4)/256; ++t) {
      int cb  = (t*4 + wv)*64;
      int ch  = cb + lane;
      int row = ch >> 2, cp = ch & 3;
      int gp  = cp ^ (row & 3) ^ ((row >> 2) & 1);
      long long gb = (long long)(n0 + row)*ldb + (kt + gp*8);
      gld16(&Bs[cb*8], Bt + gb);
    }
    __syncthreads();
    bf16x8 af[FM], bfr[FN];
#pragma unroll
    for (int mi=0; mi<FM; ++mi) {
      int row = wr*WM + mi*16 + (lane & 15);
      int cp  = (lane >> 4) ^ (row & 3) ^ ((row >> 2) & 1);
      af[mi] = *reinterpret_cast<const bf16x8*>(&As[row*BK + cp*8]);
    }
#pragma unroll
    for (int ni=0; ni<FN; ++ni) {
      int row = wc*WN + ni*16 + (lane & 15);
      int cp  = (lane >> 4) ^ (row & 3) ^ ((row >> 2) & 1);
      bfr[ni] = *reinterpret_cast<const bf16x8*>(&Bs[row*BK + cp*8]);
    }
#pragma unroll
    for (int mi=0; mi<FM; ++mi)
#pragma unroll
      for (int ni=0; ni<FN; ++ni)
        acc[mi][ni] = __builtin_amdgcn_mfma_f32_16x16x32_bf16(af[mi], bfr[ni], acc[mi][ni], 0,0,0);
    __syncthreads();
  }

#pragma unroll
  for (int mi=0; mi<FM; ++mi)
#pragma unroll
  for (int ni=0; ni<FN; ++ni)
#pragma unroll
  for (int r=0; r<4; ++r) {
    int m = m0 + wr*WM + mi*16 + ((lane>>4)<<2) + r;
    int n = n0 + wc*WN + ni*16 + (lane & 15);
    float v = acc[mi][ni][r];
    if constexpr (MODE==5) {
      int seg = n / 768, nn = n - seg*768;
      u16* dst = seg==0 ? Cb : (seg==1 ? Cb2 : Cb3);
      dst[(long long)m*768 + nn] = f2b(v);
    } else {
      long long ci = (long long)m*ldc + n;
      if constexpr (EPI==0) Cf[ci] = v; else Cb[ci] = f2b(v);
    }
  }
}

// ================= fused sliding-window attention =================
__global__ __launch_bounds__(256) void sw_attn_k(
    const u16* __restrict__ Qm, const u16* __restrict__ Km,
    const u16* __restrict__ Vt, u16* __restrict__ Om)
{
  __shared__ __attribute__((aligned(16))) u16 Kb_s[64*64];
  __shared__ __attribute__((aligned(16))) u16 Vb_s[64*64];
  __shared__ __attribute__((aligned(16))) u16 Pb_s[4*32*64];
  const int tid = threadIdx.x, lane = tid & 63, wv = tid >> 6;
  const int qc = blockIdx.x >> 1, half = blockIdx.x & 1;
  const int h = blockIdx.y, b = blockIdx.z;
  const int q0 = qc*256 + half*128 + wv*32;
  const long long rowbase = (long long)b*SL;

  bf16x8 Qf[2][2];
#pragma unroll
  for (int mi=0;mi<2;++mi)
#pragma unroll
    for (int ks=0;ks<2;++ks)
      Qf[mi][ks] = *(const bf16x8*)(Qm + (rowbase + q0 + mi*16 + (lane&15))*DM + h*DH + ks*32 + (lane>>4)*8);

  f32x4 accO[2][4] = {};
  float mrun[2][4], lrun[2][4];
#pragma unroll
  for (int mi=0;mi<2;++mi)
#pragma unroll
    for (int r=0;r<4;++r){ mrun[mi][r]=-3e38f; lrun[mi][r]=0.f; }

  const int srow = tid >> 3;
  const int schunk = (tid & 7) ^ (srow & 7);

  const int kb0 = qc*256 + half*128 - 256;
  const int slo = kb0 < 0 ? ((-kb0) >> 6) : 0;
  const int shi_t = (SL - kb0) >> 6;
  const int shi = shi_t < 10 ? shi_t : 10;

  const int qpb = q0 + ((lane>>4)<<2);

  for (int s = slo; s < shi; ++s) {
    const int kb = kb0 + s*64;
#pragma unroll
    for (int ii=0; ii<2; ++ii) {
      gld16(Kb_s + ii*2048 + wv*512,
            Km + (rowbase + kb + srow + ii*32)*DM + h*DH + schunk*8);
      gld16(Vb_s + ii*2048 + wv*512,
            Vt + ((long long)b*DM + h*DH + srow + ii*32)*SL + kb + schunk*8);
    }
    asm volatile("s_waitcnt vmcnt(0)" ::: "memory");
    __syncthreads();

    f32x4 accS[2][4] = {};
    {
      bf16x8 Kf[4][2];
#pragma unroll
      for (int nf=0;nf<4;++nf){
        int row = nf*16 + (lane&15);
#pragma unroll
        for (int ks=0;ks<2;++ks){
          int ch = ((lane>>4) + ks*4) ^ (row&7);
          Kf[nf][ks] = *(const bf16x8*)(Kb_s + row*64 + ch*8);
        }
      }
#pragma unroll
      for (int mi=0;mi<2;++mi)
#pragma unroll
        for (int nf=0;nf<4;++nf){
          accS[mi][nf] = __builtin_amdgcn_mfma_f32_16x16x32_bf16(Qf[mi][0], Kf[nf][0], accS[mi][nf], 0,0,0);
          accS[mi][nf] = __builtin_amdgcn_mfma_f32_16x16x32_bf16(Qf[mi][1], Kf[nf][1], accS[mi][nf], 0,0,0);
        }
    }

    float smax[2][4];
#pragma unroll
    for (int mi=0;mi<2;++mi)
#pragma unroll
      for (int r=0;r<4;++r) smax[mi][r] = -3e38f;
#pragma unroll
    for (int mi=0;mi<2;++mi)
#pragma unroll
      for (int nf=0;nf<4;++nf)
#pragma unroll
        for (int r=0;r<4;++r){
          int dd = (kb + nf*16 + (lane&15)) - (qpb + mi*16 + r);
          bool ok = (dd <= 256) && (dd >= -256);
          float v = ok ? accS[mi][nf][r]*0.125f : -3e38f;
          accS[mi][nf][r] = v;
          smax[mi][r] = fmaxf(smax[mi][r], v);
        }
#pragma unroll
    for (int mi=0;mi<2;++mi)
#pragma unroll
      for (int r=0;r<4;++r){
        float v = smax[mi][r];
        v = fmaxf(v, __shfl_xor(v,1,64)); v = fmaxf(v, __shfl_xor(v,2,64));
        v = fmaxf(v, __shfl_xor(v,4,64)); v = fmaxf(v, __shfl_xor(v,8,64));
        smax[mi][r] = v;
      }

#pragma unroll
    for (int mi=0;mi<2;++mi)
#pragma unroll
      for (int r=0;r<4;++r){
        float mn = fmaxf(mrun[mi][r], smax[mi][r]);
        float sc = __expf(mrun[mi][r] - mn);
        float ls = 0.f;
#pragma unroll
        for (int nf=0;nf<4;++nf){
          float sv = accS[mi][nf][r];
          float p = (sv > -1e37f) ? __expf(sv - mn) : 0.f;
          accS[mi][nf][r] = p;
          ls += p;
        }
        ls += __shfl_xor(ls,1,64); ls += __shfl_xor(ls,2,64);
        ls += __shfl_xor(ls,4,64); ls += __shfl_xor(ls,8,64);
        lrun[mi][r] = lrun[mi][r]*sc + ls;
        mrun[mi][r] = mn;
#pragma unroll
        for (int df=0;df<4;++df) accO[mi][df][r] *= sc;
      }
#pragma unroll
    for (int mi=0;mi<2;++mi)
#pragma unroll
      for (int nf=0;nf<4;++nf)
#pragma unroll
        for (int r=0;r<4;++r){
          int ql = mi*16 + ((lane>>4)<<2) + r;
          int k  = nf*16 + (lane&15);
          int ch = (k>>3) ^ (ql&7);
          Pb_s[wv*2048 + ql*64 + ch*8 + (k&7)] = f2b(accS[mi][nf][r]);
        }
    asm volatile("s_waitcnt lgkmcnt(0)" ::: "memory");
    __builtin_amdgcn_sched_barrier(0);

    {
      bf16x8 Pf[2][2], Vf[4][2];
#pragma unroll
      for (int mi=0;mi<2;++mi){
        int ql = mi*16 + (lane&15);
#pragma unroll
        for (int ks=0;ks<2;++ks){
          int ch = ((lane>>4) + ks*4) ^ (ql&7);
          Pf[mi][ks] = *(const bf16x8*)(Pb_s + wv*2048 + ql*64 + ch*8);
        }
      }
#pragma unroll
      for (int df=0;df<4;++df){
        int dr = df*16 + (lane&15);
#pragma unroll
        for (int ks=0;ks<2;++ks){
          int ch = ((lane>>4) + ks*4) ^ (dr&7);
          Vf[df][ks] = *(const bf16x8*)(Vb_s + dr*64 + ch*8);
        }
      }
#pragma unroll
      for (int mi=0;mi<2;++mi)
#pragma unroll
        for (int df=0;df<4;++df){
          accO[mi][df] = __builtin_amdgcn_mfma_f32_16x16x32_bf16(Pf[mi][0], Vf[df][0], accO[mi][df], 0,0,0);
          accO[mi][df] = __builtin_amdgcn_mfma_f32_16x16x32_bf16(Pf[mi][1], Vf[df][1], accO[mi][df], 0,0,0);
        }
    }
    __syncthreads();
  }

#pragma unroll
  for (int mi=0;mi<2;++mi)
#pragma unroll
    for (int df=0;df<4;++df)
#pragma unroll
      for (int r=0;r<4;++r){
        long long row = rowbase + qpb + mi*16 + r;
        int col = h*DH + df*16 + (lane&15);
        Om[row*DM + col] = f2b(accO[mi][df][r] / lrun[mi][r]);
      }
}

// ---------------- pointwise / small kernels ----------------
__global__ __launch_bounds__(256) void embed_ln_k(const int* __restrict__ x,
    const float* __restrict__ emb, const float* __restrict__ pos,
    const float* __restrict__ g, const float* __restrict__ bta,
    float* __restrict__ of, u16* __restrict__ ob)
{
  __shared__ float sm[4];
  const int row = blockIdx.x, s = row & (SL-1);
  const long long tok = x[row];
  const float* e = emb + tok*DM;
  const float* p = pos + (long long)s*DM;
  float v[3], su=0.f, sq=0.f;
#pragma unroll
  for (int i=0;i<3;++i){ int d=threadIdx.x+i*256; v[i]=e[d]+p[d]; su+=v[i]; sq+=v[i]*v[i]; }
  su = bred_sum(su, sm); sq = bred_sum(sq, sm);
  float mean = su*(1.f/DM), var = sq*(1.f/DM)-mean*mean, rs = rsqrtf(var+1e-5f);
#pragma unroll
  for (int i=0;i<3;++i){ int d=threadIdx.x+i*256;
    float o = (v[i]-mean)*rs*g[d] + bta[d];
    of[(long long)row*DM+d]=o; ob[(long long)row*DM+d]=f2b(o); }
}

// a + c -> LN
__global__ __launch_bounds__(256) void resid_ln_k(const float* __restrict__ a, const float* __restrict__ c,
    const float* __restrict__ g, const float* __restrict__ bta,
    float* __restrict__ of, u16* __restrict__ ob)
{
  __shared__ float sm[4];
  const long long row = blockIdx.x;
  const float* ra = a + row*DM;
  const float* rc = c + row*DM;
  float v[3], su=0.f, sq=0.f;
#pragma unroll
  for (int i=0;i<3;++i){
    int d=threadIdx.x+i*256;
    v[i]=ra[d]+rc[d];
    su+=v[i]; sq+=v[i]*v[i];
  }
  su = bred_sum(su, sm); sq = bred_sum(sq, sm);
  float mean = su*(1.f/DM), var = sq*(1.f/DM)-mean*mean, rs = rsqrtf(var+1e-5f);
#pragma unroll
  for (int i=0;i<3;++i){ int d=threadIdx.x+i*256;
    float o = (v[i]-mean)*rs*g[d] + bta[d];
    of[row*DM+d]=o; if (ob) ob[row*DM+d]=f2b(o); }
}

// fp32 [Kd,Nd] -> bf16 [Nd,Kd]
__global__ __launch_bounds__(256) void transp_w_k(const float* __restrict__ W, u16* __restrict__ Wt, int Kd, int Nd)
{
  __shared__ float t[32][33];
  int n0 = blockIdx.x*32, k0 = blockIdx.y*32;
  int lx = threadIdx.x & 31, ly = threadIdx.x >> 5;
#pragma unroll
  for (int i=0;i<4;++i) t[ly+i*8][lx] = W[(long long)(k0+ly+i*8)*Nd + n0+lx];
  __syncthreads();
#pragma unroll
  for (int i=0;i<4;++i) Wt[(long long)(n0+ly+i*8)*Kd + k0+lx] = f2b(t[lx][ly+i*8]);
}

// bf16 [8192,Nc] -> bf16 [B][Nc][SL]
__global__ __launch_bounds__(256) void transp_b_k(const u16* __restrict__ in, u16* __restrict__ out, int Nc)
{
  __shared__ u16 t[32][33];
  int c0 = blockIdx.x*32, r0 = blockIdx.y*32;
  int lx = threadIdx.x & 31, ly = threadIdx.x >> 5;
#pragma unroll
  for (int i=0;i<4;++i) t[ly+i*8][lx] = in[(long long)(r0+ly+i*8)*Nc + c0+lx];
  __syncthreads();
  int b = r0 >> 11, s0 = r0 & (SL-1);
#pragma unroll
  for (int i=0;i<4;++i) out[((long long)b*Nc + c0+ly+i*8)*SL + s0+lx] = t[lx][ly+i*8];
}

// outer-MHA softmax: one wave per row, in-place on pre-scaled bf16 scores
__global__ __launch_bounds__(256) void mha_softmax_k(u16* __restrict__ sc, const int* __restrict__ x)
{
  const int r = blockIdx.x*4 + (threadIdx.x >> 6);
  const int lane = threadIdx.x & 63;
  const int z = r >> 11;
  const int b = z >> 2;
  u16* row = sc + (long long)z*SL*SL + (long long)(r & (SL-1))*SL;
  const int* xb = x + b*SL;
  float v[32]; float mx = -3e38f;
#pragma unroll
  for (int i=0;i<4;++i){
    const int j0 = i*512 + lane*8;
    u16x8 pv = *(const u16x8*)(row + j0);
    i32x4 xa = *(const i32x4*)(xb + j0);
    i32x4 xc = *(const i32x4*)(xb + j0 + 4);
#pragma unroll
    for (int e=0;e<8;++e){
      int xv = e<4 ? xa[e] : xc[e-4];
      float f = (xv != 0) ? b2f(pv[e]) : -3e38f;
      v[i*8+e] = f;
      mx = fmaxf(mx, f);
    }
  }
  mx = wred_max(mx);
  float s = 0.f;
#pragma unroll
  for (int i=0;i<32;++i){ v[i] = (v[i] > -1e37f) ? __expf(v[i]-mx) : 0.f; s += v[i]; }
  s = wred_sum(s);
  float inv = 1.f/s;
#pragma unroll
  for (int i=0;i<4;++i){
    u16x8 ov;
#pragma unroll
    for (int e=0;e<8;++e) ov[e] = f2b(v[i*8+e]*inv);
    *(u16x8*)(row + i*512 + lane*8) = ov;
  }
}

__global__ __launch_bounds__(256) void pool_part_k(const float* __restrict__ f, float* __restrict__ pp)
{
  int b = blockIdx.x, ch = blockIdx.y;
  float m0=-3e38f, m1=-3e38f, m2=-3e38f;
  for (int s = ch*128; s < ch*128+128; ++s){
    const float* r = f + ((long long)b*SL + s)*DM;
    m0=fmaxf(m0,r[threadIdx.x]); m1=fmaxf(m1,r[threadIdx.x+256]); m2=fmaxf(m2,r[threadIdx.x+512]);
  }
  float* o = pp + (long long)(b*16+ch)*DM;
  o[threadIdx.x]=m0; o[threadIdx.x+256]=m1; o[threadIdx.x+512]=m2;
}

__global__ __launch_bounds__(256) void pool_red_k(const float* __restrict__ pp, float* __restrict__ out)
{
  int b = blockIdx.x;
#pragma unroll
  for (int i=0;i<3;++i){
    int d = threadIdx.x + i*256;
    float m = -3e38f;
    for (int c=0;c<16;++c) m = fmaxf(m, pp[(long long)(b*16+c)*DM + d]);
    out[(long long)b*DM + d] = m;
  }
}

// ---------------- orchestration ----------------
extern "C" void kernel_launch(void* const* d_in, const int* in_sizes, int n_in,
                              void* d_out, int out_size, void* d_ws, size_t ws_size,
                              hipStream_t stream)
{
  const int*   x      = (const int*)  d_in[0];
  const float* emb    = (const float*)d_in[1];
  const float* pos    = (const float*)d_in[2];
  const float* ln_e_g = (const float*)d_in[3];
  const float* ln_e_b = (const float*)d_in[4];
  const float* lf_wq  = (const float*)d_in[5];
  const float* lf_wk  = (const float*)d_in[6];
  const float* lf_wv  = (const float*)d_in[7];
  const float* lf_wo  = (const float*)d_in[8];
  const float* ln1_g  = (const float*)d_in[9];
  const float* ln1_b  = (const float*)d_in[10];
  const float* w1     = (const float*)d_in[11];
  const float* w2     = (const float*)d_in[12];
  const float* ln2_g  = (const float*)d_in[13];
  const float* ln2_b  = (const float*)d_in[14];
  const float* mha_wq = (const float*)d_in[15];
  const float* mha_wk = (const float*)d_in[16];
  const float* mha_wv = (const float*)d_in[17];
  const float* mha_fc = (const float*)d_in[18];
  const float* mha_ln_g = (const float*)d_in[19];
  const float* mha_ln_b = (const float*)d_in[20];

  (void)hipFuncSetAttribute((const void*)gemm256_k<0,2>, hipFuncAttributeMaxDynamicSharedMemorySize, 131072);
  (void)hipFuncSetAttribute((const void*)gemm256_k<1,3>, hipFuncAttributeMaxDynamicSharedMemorySize, 131072);
  (void)hipFuncSetAttribute((const void*)gemm256_k<3,1>, hipFuncAttributeMaxDynamicSharedMemorySize, 131072);
  (void)hipFuncSetAttribute((const void*)gemm128n_k,     hipFuncAttributeMaxDynamicSharedMemorySize, 98304);

  const long long R = 8192;           // B*S rows
  float* F0 = (float*)d_ws;           // h / out_lf (fp32)
  float* F1 = F0 + R*DM;              // gemm fp32 out
  float* F2 = F1 + R*DM;              // h2 / final ln
  u16* B0 = (u16*)(F2 + R*DM);        // h bf16 -> attn-out bf16
  u16* B1 = B0 + R*DM;                // lf q -> h2 bf16
  u16* B2 = B1 + R*DM;                // lf k -> out_lf bf16
  u16* B3 = B2 + R*DM;                // lf v^T [B][768][SL]
  u16* WT = B3 + R*DM;                // transposed weights (bf16, up to 9216x768)
  u16* G1 = WT + (long long)9216*DM;  // gelu-out / mha q
  u16* G2 = G1 + R*DFF;               // mha k -> mha o
  u16* G3 = G2 + R*DFF;               // mha v^T [B][3072][SL]
  u16* SC = G3 + R*DFF;               // lf/mha v temp, mha P (134MB)
  float* PP = (float*)(SC + (long long)16*SL*SL);   // pool partials

  dim3 T(256), T5(512);
  const size_t SM256 = 131072, SM128 = 98304;

  // ---- longformer layer
  embed_ln_k<<<dim3(8192), T, 0, stream>>>(x, emb, pos, ln_e_g, ln_e_b, F0, B0);

  // fused lf qkv: WT = [q|k|v]^T (2304x768), scatter -> B1,B2,SC
  transp_w_k<<<dim3(24,24), T, 0, stream>>>(lf_wq, WT,               DM, DM);
  transp_w_k<<<dim3(24,24), T, 0, stream>>>(lf_wk, WT + 768*768,     DM, DM);
  transp_w_k<<<dim3(24,24), T, 0, stream>>>(lf_wv, WT + 2*768*768,   DM, DM);
  gemm_k<128,128,5,1><<<dim3(64,18), T, 0, stream>>>(B0, WT, nullptr, B1, B2, SC, DM, DM, DM, 0);
  transp_b_k<<<dim3(24,256), T, 0, stream>>>(SC, B3, DM);

  sw_attn_k<<<dim3(16,12,4), T, 0, stream>>>(B1, B2, B3, B0);

  transp_w_k<<<dim3(24,24), T, 0, stream>>>(lf_wo, WT, DM, DM);
  gemm_k<128,128,0,0><<<dim3(64,6), T, 0, stream>>>(B0, WT, F1, nullptr, nullptr, nullptr, DM, DM, DM, DM);
  resid_ln_k<<<dim3(8192), T, 0, stream>>>(F0, F1, ln1_g, ln1_b, F2, B1);

  transp_w_k<<<dim3(96,24), T, 0, stream>>>(w1, WT, DM, DFF);
  gemm256_k<0,2><<<dim3(32,12,1), T5, SM256, stream>>>(B1, WT, nullptr, G1, nullptr, nullptr, DM, DM, DM, DFF);
  transp_w_k<<<dim3(24,96), T, 0, stream>>>(w2, WT, DFF, DM);
  gemm_k<128,128,0,0><<<dim3(64,6), T, 0, stream>>>(G1, WT, F1, nullptr, nullptr, nullptr, DFF, DFF, DFF, DM);
  resid_ln_k<<<dim3(8192), T, 0, stream>>>(F2, F1, ln2_g, ln2_b, F0, B2);

  // ---- outer MHA: fused qkv (WT = [wq|wk|wv]^T 9216x768), scatter -> G1,G2,SC
  transp_w_k<<<dim3(96,24), T, 0, stream>>>(mha_wq, WT,                 DM, DFF);
  transp_w_k<<<dim3(96,24), T, 0, stream>>>(mha_wk, WT + (long long)3072*768, DM, DFF);
  transp_w_k<<<dim3(96,24), T, 0, stream>>>(mha_wv, WT + (long long)6144*768, DM, DFF);
  gemm256_k<3,1><<<dim3(32,36,1), T5, SM256, stream>>>(B2, WT, nullptr, G1, G2, SC, DM, DM, DM, 0);
  transp_b_k<<<dim3(96,256), T, 0, stream>>>(SC, G3, DFF);

  gemm256_k<1,3><<<dim3(8,8,16), T5, SM256, stream>>>(G1, G2, nullptr, SC, nullptr, nullptr, DKM, 3072, 3072, 0);
  mha_softmax_k<<<dim3(8192), T, 0, stream>>>(SC, x);
  gemm128n_k<<<dim3(8,6,16), T5, SM128, stream>>>(SC, G3, G2, SL);

  transp_w_k<<<dim3(24,96), T, 0, stream>>>(mha_fc, WT, DFF, DM);
  gemm_k<128,128,0,0><<<dim3(64,6), T, 0, stream>>>(G2, WT, F1, nullptr, nullptr, nullptr, DFF, DFF, DFF, DM);
  resid_ln_k<<<dim3(8192), T, 0, stream>>>(F0, F1, mha_ln_g, mha_ln_b, F2, nullptr);

  pool_part_k<<<dim3(4,16), T, 0, stream>>>(F2, PP);
  pool_red_k<<<dim3(4), T, 0, stream>>>(PP, (float*)d_out);
}